// Round 17
// baseline (262.601 us; speedup 1.0000x reference)
//
#include <hip/hip_runtime.h>

#define DEV __device__ __forceinline__

using bf16x8 = __attribute__((ext_vector_type(8))) short;
using f32x4  = __attribute__((ext_vector_type(4))) float;
using u16 = unsigned short;

constexpr int S_   = 2048;
constexpr int D_   = 1024;
constexpr int M_   = 4096;   // B*S tokens
constexpr int WIN_ = 256;
constexpr float SCALE_ = 0.125f;

typedef const __attribute__((address_space(1))) void* gptr_t;
typedef __attribute__((address_space(3))) void* lptr_t;

DEV u16 f2bf(float f) {
  unsigned u = __builtin_bit_cast(unsigned, f);
  return (u16)((u + 0x7fffu + ((u >> 16) & 1u)) >> 16);
}
DEV float bf2f(u16 b) {
  unsigned u = ((unsigned)b) << 16;
  return __builtin_bit_cast(float, u);
}

// ---------------- merged preprocessing: all weight transposes + adaln partials
__global__ __launch_bounds__(256) void prep_all(const float* __restrict__ wq,
                                                const float* __restrict__ wk,
                                                const float* __restrict__ wv,
                                                const float* __restrict__ wo,
                                                const float* __restrict__ w1,
                                                const float* __restrict__ w3,
                                                const float* __restrict__ w2,
                                                const float* __restrict__ cond,
                                                const float* __restrict__ aaw,
                                                const float* __restrict__ afw,
                                                u16* wt_qkv, u16* wt_o,
                                                u16* wt_13, u16* wt_2,
                                                float* part) {
  __shared__ float tile[32][33];
  __shared__ float sc[128];
  int idx = blockIdx.x;
  int tx = threadIdx.x & 31, ty = threadIdx.x >> 5;
  if (idx < 4096) {
    int z = idx >> 10, t = idx & 1023;
    const float* src; u16* dst;
    switch (z) {
      case 0: src = wq; dst = wt_qkv; break;
      case 1: src = wk; dst = wt_qkv + 1048576; break;
      case 2: src = wv; dst = wt_qkv + 2097152; break;
      default: src = wo; dst = wt_o;
    }
    int n0 = (t & 31) * 32, k0 = (t >> 5) * 32;
#pragma unroll
    for (int p = 0; p < 4; ++p)
      tile[ty + p * 8][tx] = src[(size_t)(k0 + ty + p * 8) * 1024 + n0 + tx];
    __syncthreads();
#pragma unroll
    for (int p = 0; p < 4; ++p)
      dst[(size_t)(n0 + ty + p * 8) * 1024 + k0 + tx] = f2bf(tile[tx][ty + p * 8]);
  } else if (idx < 12288) {
    int i2 = idx - 4096;
    int z = i2 >> 12, t = i2 & 4095;
    const float* src = z ? w3 : w1;
    int add = z ? 16 : 0;
    int n0 = (t & 127) * 32, k0 = (t >> 7) * 32;
#pragma unroll
    for (int p = 0; p < 4; ++p)
      tile[ty + p * 8][tx] = src[(size_t)(k0 + ty + p * 8) * 4096 + n0 + tx];
    __syncthreads();
#pragma unroll
    for (int p = 0; p < 4; ++p) {
      int n = n0 + ty + p * 8;
      int r = ((n >> 4) << 5) + add + (n & 15);
      wt_13[(size_t)r * 1024 + k0 + tx] = f2bf(tile[tx][ty + p * 8]);
    }
  } else if (idx < 16384) {
    int i3 = idx - 12288;
    int n0 = (i3 & 31) * 32, k0 = (i3 >> 5) * 32;
#pragma unroll
    for (int p = 0; p < 4; ++p)
      tile[ty + p * 8][tx] = w2[(size_t)(k0 + ty + p * 8) * 1024 + n0 + tx];
    __syncthreads();
#pragma unroll
    for (int p = 0; p < 4; ++p)
      wt_2[(size_t)(n0 + ty + p * 8) * 4096 + k0 + tx] = f2bf(tile[tx][ty + p * 8]);
  } else {
    int p = idx - 16384;
    int xb = p % 12;
    int rest = p / 12;
    int ks = rest & 7, sb = rest >> 3;
    int b = sb & 1;
    const float* W = (sb & 2) ? afw : aaw;
    if (threadIdx.x < 128) {
      float c = cond[b * 1024 + ks * 128 + threadIdx.x];
      sc[threadIdx.x] = c / (1.f + __expf(-c));
    }
    __syncthreads();
    int n = xb * 256 + threadIdx.x;
    float acc = 0.f;
    const float* Wp = W + (size_t)(ks * 128) * 3072 + n;
#pragma unroll 4
    for (int c = 0; c < 128; ++c) acc += sc[c] * Wp[(size_t)c * 3072];
    part[(size_t)(sb * 8 + ks) * 3072 + n] = acc;
  }
}

__global__ __launch_bounds__(256) void adaln_reduce(const float* __restrict__ part,
                                                    const float* __restrict__ ba,
                                                    const float* __restrict__ bfb,
                                                    float* __restrict__ modout) {
  int n = blockIdx.x * 256 + threadIdx.x;
  int sb = blockIdx.y;
  float acc = ((sb & 2) ? bfb : ba)[n];
#pragma unroll
  for (int k = 0; k < 8; ++k) acc += part[(size_t)(sb * 8 + k) * 3072 + n];
  modout[sb * 3072 + n] = acc;
}

// ---------------- LayerNorm + (1+scale)*x + shift -> bf16
__global__ __launch_bounds__(256) void ln_mod_kernel(const float* __restrict__ x,
                                                     const float* __restrict__ modset,
                                                     u16* __restrict__ out) {
  int m = blockIdx.x;
  int b = m >> 11;
  int tid = threadIdx.x;
  const float4* row = reinterpret_cast<const float4*>(x + (size_t)m * D_);
  float4 v = row[tid];
  float s = v.x + v.y + v.z + v.w;
  float ss = v.x * v.x + v.y * v.y + v.z * v.z + v.w * v.w;
#pragma unroll
  for (int o = 1; o < 64; o <<= 1) { s += __shfl_xor(s, o); ss += __shfl_xor(ss, o); }
  __shared__ float rs[4], rq[4];
  if ((tid & 63) == 0) { rs[tid >> 6] = s; rq[tid >> 6] = ss; }
  __syncthreads();
  s = rs[0] + rs[1] + rs[2] + rs[3];
  ss = rq[0] + rq[1] + rq[2] + rq[3];
  float mu = s * (1.f / D_);
  float rinv = rsqrtf(ss * (1.f / D_) - mu * mu + 1e-5f);
  int n = tid * 4;
  const float* mb = modset + b * 3072;
  float4 sh = *reinterpret_cast<const float4*>(mb + n);
  float4 sc = *reinterpret_cast<const float4*>(mb + 1024 + n);
  ushort4 o4;
  o4.x = f2bf((v.x - mu) * rinv * (1.f + sc.x) + sh.x);
  o4.y = f2bf((v.y - mu) * rinv * (1.f + sc.y) + sh.y);
  o4.z = f2bf((v.z - mu) * rinv * (1.f + sc.z) + sh.z);
  o4.w = f2bf((v.w - mu) * rinv * (1.f + sc.w) + sh.w);
  *reinterpret_cast<ushort4*>(out + (size_t)m * D_ + n) = o4;
}

// ---------------- rotate 4 (even,odd) bf16 pairs
DEV bf16x8 rope8(bf16x8 v, const float* __restrict__ cs, const float* __restrict__ sn,
                 int s, int base) {
  bf16x8 r;
#pragma unroll
  for (int t = 0; t < 4; ++t) {
    float c = cs[s * 32 + base + t], si = sn[s * 32 + base + t];
    float x = bf2f((u16)v[2 * t]), y = bf2f((u16)v[2 * t + 1]);
    r[2 * t] = (short)f2bf(x * c - y * si);
    r[2 * t + 1] = (short)f2bf(x * si + y * c);
  }
  return r;
}

// ---------------- RoPE on K plane only (in-place, once per token)
__global__ __launch_bounds__(256) void rope_k(u16* __restrict__ qkv,
                                              const float* __restrict__ cs,
                                              const float* __restrict__ sn) {
  int idx = blockIdx.x * 256 + threadIdx.x;
  int i = idx & 31;
  int hh = (idx >> 5) & 15;
  int mm = idx >> 9;
  int s = mm & (S_ - 1);
  float c = cs[s * 32 + i], si = sn[s * 32 + i];
  unsigned* kp = reinterpret_cast<unsigned*>(qkv + (size_t)mm * 3072 + 1024 + hh * 64 + 2 * i);
  unsigned kv = *kp;
  float kx = bf2f((u16)(kv & 0xffff)), ky = bf2f((u16)(kv >> 16));
  *kp = (unsigned)f2bf(kx * c - ky * si) | ((unsigned)f2bf(kx * si + ky * c) << 16);
}

// ---------------- MFMA sliding-window flash attention, KVBLK=64 (K pre-roped; Q roped at load)
__global__ __launch_bounds__(256) void attn_mfma(const u16* __restrict__ qkv,
                                                 const float* __restrict__ cs,
                                                 const float* __restrict__ sn,
                                                 u16* __restrict__ out) {
  int q0 = blockIdx.x * 64;
  int h = blockIdx.y, b = blockIdx.z;
  __shared__ __align__(16) u16 Ks[4096];
  __shared__ __align__(16) u16 Vt[4096];
  __shared__ __align__(16) u16 Ps[4][16][72];
  int tid = threadIdx.x, lane = tid & 63, w = tid >> 6;
  int l4 = lane >> 4, lc = lane & 15;
  int sq = q0 + w * 16 + lc;
  const u16* qrow = qkv + (size_t)(b * S_ + sq) * 3072 + h * 64;
  bf16x8 aq0 = rope8(*reinterpret_cast<const bf16x8*>(qrow + l4 * 8), cs, sn, sq, l4 * 4);
  bf16x8 aq1 = rope8(*reinterpret_cast<const bf16x8*>(qrow + 32 + l4 * 8), cs, sn, sq, 16 + l4 * 4);
  int qw0 = q0 + w * 16;
  float mrow[4], lsum[4];
  f32x4 oacc[4];
#pragma unroll
  for (int r = 0; r < 4; ++r) {
    mrow[r] = -__builtin_inff(); lsum[r] = 0.f;
    oacc[r] = f32x4{0.f, 0.f, 0.f, 0.f};
  }
  int kj = lane >> 3;
  int kcb = (lane & 7) * 16;
  int vj = tid & 63;
  int vd0h = (tid >> 6) * 8;
  int jstart = q0 - WIN_; if (jstart < 0) jstart = 0;
  for (int jb = jstart; jb < q0 + 64; jb += 64) {
    __syncthreads();
#pragma unroll
    for (int c = 0; c < 2; ++c) {
      int j = c * 32 + w * 8 + kj;
      const char* src = reinterpret_cast<const char*>(
          qkv + (size_t)(b * S_ + jb + j) * 3072 + 1024 + h * 64) + (kcb ^ ((j & 7) << 4));
      __builtin_amdgcn_global_load_lds((gptr_t)src,
          (lptr_t)(reinterpret_cast<char*>(Ks) + c * 4096 + w * 1024), 16, 0, 0);
    }
#pragma unroll
    for (int half = 0; half < 2; ++half) {
      int dbase = vd0h + half * 32;
      bf16x8 v = *reinterpret_cast<const bf16x8*>(
          qkv + (size_t)(b * S_ + jb + vj) * 3072 + 2048 + h * 64 + dbase);
#pragma unroll
      for (int k2 = 0; k2 < 8; ++k2) {
        int d = dbase + k2;
        int cb = (2 * vj) ^ ((d & 7) << 4);
        *reinterpret_cast<u16*>(reinterpret_cast<char*>(Vt) + d * 128 + cb) = (u16)v[k2];
      }
    }
    __syncthreads();
    if (jb + 63 >= qw0 - WIN_ && jb <= qw0 + 15) {
      f32x4 sacc[4] = {f32x4{0,0,0,0}, f32x4{0,0,0,0}, f32x4{0,0,0,0}, f32x4{0,0,0,0}};
      __builtin_amdgcn_s_setprio(1);
#pragma unroll
      for (int jt = 0; jt < 4; ++jt) {
        int j = jt * 16 + lc;
#pragma unroll
        for (int kh = 0; kh < 2; ++kh) {
          int cbb = (kh * 64 + l4 * 16) ^ ((j & 7) << 4);
          bf16x8 bk = *reinterpret_cast<const bf16x8*>(
              reinterpret_cast<char*>(Ks) + j * 128 + cbb);
          sacc[jt] = __builtin_amdgcn_mfma_f32_16x16x32_bf16(kh == 0 ? aq0 : aq1, bk, sacc[jt], 0, 0, 0);
        }
      }
      __builtin_amdgcn_s_setprio(0);
      float pv[4][4], rr[4];
#pragma unroll
      for (int r = 0; r < 4; ++r) {
        int qa = qw0 + l4 * 4 + r;
        float se[4];
        float cm = -__builtin_inff();
#pragma unroll
        for (int jt = 0; jt < 4; ++jt) {
          int ja = jb + jt * 16 + lc;
          bool val = (ja <= qa) && (qa - ja <= WIN_);
          se[jt] = val ? sacc[jt][r] * SCALE_ : -__builtin_inff();
          cm = fmaxf(cm, se[jt]);
        }
        cm = fmaxf(cm, __shfl_xor(cm, 1));
        cm = fmaxf(cm, __shfl_xor(cm, 2));
        cm = fmaxf(cm, __shfl_xor(cm, 4));
        cm = fmaxf(cm, __shfl_xor(cm, 8));
        float mnew = fmaxf(mrow[r], cm);
        float esum = 0.f;
#pragma unroll
        for (int jt = 0; jt < 4; ++jt) {
          float e = __expf(se[jt] - mnew);
          e = (se[jt] == -__builtin_inff()) ? 0.f : e;
          pv[jt][r] = e;
          esum += e;
        }
        esum += __shfl_xor(esum, 1);
        esum += __shfl_xor(esum, 2);
        esum += __shfl_xor(esum, 4);
        esum += __shfl_xor(esum, 8);
        float rf = __expf(mrow[r] - mnew);
        rf = (mnew == -__builtin_inff()) ? 0.f : rf;
        rr[r] = rf;
        lsum[r] = lsum[r] * rf + esum;
        mrow[r] = mnew;
      }
#pragma unroll
      for (int jt = 0; jt < 4; ++jt)
#pragma unroll
        for (int r = 0; r < 4; ++r)
          Ps[w][l4 * 4 + r][jt * 16 + lc] = f2bf(pv[jt][r]);
      asm volatile("s_waitcnt lgkmcnt(0)" ::: "memory");
      __builtin_amdgcn_sched_barrier(0);
      bf16x8 ap[2];
#pragma unroll
      for (int js = 0; js < 2; ++js)
        ap[js] = *reinterpret_cast<const bf16x8*>(&Ps[w][lc][js * 32 + l4 * 8]);
      __builtin_amdgcn_s_setprio(1);
#pragma unroll
      for (int dt = 0; dt < 4; ++dt) {
        int d = dt * 16 + lc;
#pragma unroll
        for (int r = 0; r < 4; ++r) oacc[dt][r] *= rr[r];
#pragma unroll
        for (int js = 0; js < 2; ++js) {
          int cb = (js * 64 + l4 * 16) ^ ((d & 7) << 4);
          bf16x8 bv = *reinterpret_cast<const bf16x8*>(
              reinterpret_cast<char*>(Vt) + d * 128 + cb);
          oacc[dt] = __builtin_amdgcn_mfma_f32_16x16x32_bf16(ap[js], bv, oacc[dt], 0, 0, 0);
        }
      }
      __builtin_amdgcn_s_setprio(0);
    }
  }
  float inv[4];
#pragma unroll
  for (int r = 0; r < 4; ++r) inv[r] = 1.f / lsum[r];
  size_t obase = (size_t)(b * S_ + qw0) * D_ + h * 64;
#pragma unroll
  for (int dt = 0; dt < 4; ++dt)
#pragma unroll
    for (int r = 0; r < 4; ++r)
      out[obase + (size_t)(l4 * 4 + r) * D_ + dt * 16 + lc] = f2bf(oacc[dt][r] * inv[r]);
}

// ---------------- shared fragment helpers for BK=32 tiles (row stride 64 B)
DEV bf16x8 read_frag(const u16* tile, int r16, int lane) {
  int r = r16 + (lane & 15);
  int cb = ((lane >> 4) << 4) ^ (((r >> 1) & 3) << 4);
  return *reinterpret_cast<const bf16x8*>(reinterpret_cast<const char*>(tile) + r * 64 + cb);
}

DEV void stage_tile(const u16* __restrict__ src, int ld, int rowBase, int kBase,
                    u16* tile, int tid) {
#pragma unroll
  for (int c = 0; c < 2; ++c) {
    int row = c * 64 + (tid >> 2);
    int cbs = ((tid & 3) << 4) ^ (((row >> 1) & 3) << 4);
    const char* g = reinterpret_cast<const char*>(src + (size_t)(rowBase + row) * ld + kBase) + cbs;
    char* l = reinterpret_cast<char*>(tile) + c * 4096 + (tid >> 6) * 1024;
    __builtin_amdgcn_global_load_lds((gptr_t)g, (lptr_t)l, 16, 0, 0);
  }
}

DEV void stage64(const u16* __restrict__ src, int ld, int rowBase, int kBase,
                 u16* tile, int tid) {
  int row = tid >> 2;
  int cbs = ((tid & 3) << 4) ^ (((row >> 1) & 3) << 4);
  const char* g = reinterpret_cast<const char*>(src + (size_t)(rowBase + row) * ld + kBase) + cbs;
  char* l = reinterpret_cast<char*>(tile) + (tid >> 6) * 1024;
  __builtin_amdgcn_global_load_lds((gptr_t)g, (lptr_t)l, 16, 0, 0);
}

#define BAR()   asm volatile("s_barrier" ::: "memory")

// ---------------- 64x128 gemm, 4-deep pipelined, counted vmcnt (3 loads/tile)
__global__ __launch_bounds__(256, 2) void gemm64(const u16* __restrict__ A,
                                                 const u16* __restrict__ Bt,
                                                 int M, int N, int K,
                                                 float* __restrict__ Cv,
                                                 const float* __restrict__ gate,
                                                 const float* __restrict__ resid) {
  __shared__ __align__(16) u16 ldsA[4][2048];
  __shared__ __align__(16) u16 ldsB[4][4096];
  int tid = threadIdx.x;
  int lane = tid & 63;
  int w = tid >> 6;
  int wr = w >> 1, wc = w & 1;
  int m0 = blockIdx.y * 64;
  int n0 = blockIdx.x * 128;
  f32x4 zero = {0.f, 0.f, 0.f, 0.f};
  f32x4 acc[2][4];
#pragma unroll
  for (int i = 0; i < 2; ++i)
#pragma unroll
    for (int j = 0; j < 4; ++j) acc[i][j] = zero;
  int nt = K >> 5;
#pragma unroll
  for (int p = 0; p < 3; ++p) {
    stage64(A, K, m0, p << 5, &ldsA[p][0], tid);
    stage_tile(Bt, K, n0, p << 5, &ldsB[p][0], tid);
  }
  asm volatile("s_waitcnt vmcnt(6)" ::: "memory");
  BAR();
  for (int t = 0; t < nt; ++t) {
    bf16x8 af[2], bfr[4];
#pragma unroll
    for (int i = 0; i < 2; ++i) af[i] = read_frag(&ldsA[t & 3][0], wr * 32 + i * 16, lane);
#pragma unroll
    for (int i = 0; i < 4; ++i) bfr[i] = read_frag(&ldsB[t & 3][0], wc * 64 + i * 16, lane);
    if (t + 3 < nt) {
      stage64(A, K, m0, (t + 3) << 5, &ldsA[(t + 3) & 3][0], tid);
      stage_tile(Bt, K, n0, (t + 3) << 5, &ldsB[(t + 3) & 3][0], tid);
    }
    __builtin_amdgcn_s_setprio(1);
#pragma unroll
    for (int i = 0; i < 2; ++i)
#pragma unroll
      for (int j = 0; j < 4; ++j)
        acc[i][j] = __builtin_amdgcn_mfma_f32_16x16x32_bf16(af[i], bfr[j], acc[i][j], 0, 0, 0);
    __builtin_amdgcn_s_setprio(0);
    if (t + 3 < nt)      asm volatile("s_waitcnt vmcnt(6)" ::: "memory");
    else if (t + 2 < nt) asm volatile("s_waitcnt vmcnt(3)" ::: "memory");
    else                 asm volatile("s_waitcnt vmcnt(0)" ::: "memory");
    BAR();
  }
  int rowB = m0 + wr * 32 + ((lane >> 4) << 2);
  int colB = n0 + wc * 64 + (lane & 15);
#pragma unroll
  for (int i = 0; i < 2; ++i) {
#pragma unroll
    for (int j = 0; j < 4; ++j) {
      int col = colB + j * 16;
#pragma unroll
      for (int jr = 0; jr < 4; ++jr) {
        int row = rowB + i * 16 + jr;
        float v = acc[i][j][jr];
        size_t idx = (size_t)row * N + col;
        int bb = row >> 11;
        Cv[idx] = resid[idx] + gate[bb * 3072 + col] * v;
      }
    }
  }
}

// ================== 256x256 GEMM, BK=64, A 3-ring, 1 barrier/tile, 1-phase read-ahead ==================
DEV bf16x8 readFrag128(const u16* halfBase, int rowInHalf, int ks, int l4) {
  int cb = ((ks << 6) + (l4 << 4)) ^ ((rowInHalf & 7) << 4);
  return *reinterpret_cast<const bf16x8*>(
      reinterpret_cast<const char*>(halfBase) + rowInHalf * 128 + cb);
}

DEV void stageHalf(const u16* __restrict__ src, int ld, int rowBase, int kBase,
                   u16* halfBase, int tid) {
#pragma unroll
  for (int c = 0; c < 2; ++c) {
    int row = c * 64 + (tid >> 3);
    int cbs = (((tid & 7) ^ ((tid >> 3) & 7)) << 4);
    const char* g = reinterpret_cast<const char*>(src + (size_t)(rowBase + row) * ld + kBase) + cbs;
    char* l = reinterpret_cast<char*>(halfBase) + c * 8192 + (tid >> 6) * 1024;
    __builtin_amdgcn_global_load_lds((gptr_t)g, (lptr_t)l, 16, 0, 0);
  }
}

// EPI 2: bf16 store | EPI 3: fused swiglu on 16-col-interleaved B layout
template <int EPI>
__global__ __launch_bounds__(512, 1) void gemm8p(const u16* __restrict__ A,
                                                 const u16* __restrict__ Bt,
                                                 int M, int N, int K,
                                                 void* __restrict__ Cv) {
  extern __shared__ __align__(16) u16 smem[];
  u16* Abase = smem;            // 3 bufs x 16 KiB = 96 KiB
  u16* Bbase = smem + 49152;    // 2 bufs x 16 KiB = 64 KiB
  int tid = threadIdx.x, lane = tid & 63, w = tid >> 6;
  int wm = w >> 2, wn = w & 3;
  int l4 = lane >> 4, lc = lane & 15;
  int wg = ((int)blockIdx.x & 7) * ((int)gridDim.x >> 3) + ((int)blockIdx.x >> 3);
  int nby = M >> 8;
  int bx = wg / nby, by = wg % nby;
  int m0 = by << 8, n0 = bx << 8;
  int NT = K >> 6;
  f32x4 zero = {0.f, 0.f, 0.f, 0.f};
  f32x4 acc[8][4];
#pragma unroll
  for (int i = 0; i < 8; ++i)
#pragma unroll
    for (int j = 0; j < 4; ++j) acc[i][j] = zero;
  stageHalf(A, K, m0, 0, Abase, tid);
  stageHalf(A, K, m0 + 128, 0, Abase + 8192, tid);
  stageHalf(Bt, K, n0, 0, Bbase, tid);
  stageHalf(Bt, K, n0 + 128, 0, Bbase + 8192, tid);
  stageHalf(A, K, m0, 64, Abase + 16384, tid);
  stageHalf(A, K, m0 + 128, 64, Abase + 16384 + 8192, tid);
  asm volatile("s_waitcnt vmcnt(4)" ::: "memory");
  BAR();
  int rBq = (wn & 1) * 64;
  int ab = 0;   // t % 3
  for (int t = 0; t < NT; ++t) {
    const u16* Ah = Abase + ab * 16384 + wm * 8192;
    const u16* Bh = Bbase + (t & 1) * 16384 + (wn >> 1) * 8192;
    u16* Bdst = Bbase + ((t + 1) & 1) * 16384;
    int ad = ab + 2; if (ad >= 3) ad -= 3;
    u16* Adst = Abase + ad * 16384;
    int kN1 = (t + 1) << 6, kN2 = (t + 2) << 6;
    bf16x8 aLo[4][2], aHi[4][2], bL[2][2], bH[2][2];
    // ---- issue phase-1 AND phase-2 fragment reads up front (current-tile buffers only)
#pragma unroll
    for (int mi = 0; mi < 4; ++mi)
#pragma unroll
      for (int ks = 0; ks < 2; ++ks)
        aLo[mi][ks] = readFrag128(Ah, mi * 16 + lc, ks, l4);
#pragma unroll
    for (int j = 0; j < 2; ++j)
#pragma unroll
      for (int ks = 0; ks < 2; ++ks)
        bL[j][ks] = readFrag128(Bh, rBq + j * 16 + lc, ks, l4);
#pragma unroll
    for (int mi = 0; mi < 4; ++mi)
#pragma unroll
      for (int ks = 0; ks < 2; ++ks)
        aHi[mi][ks] = readFrag128(Ah, 64 + mi * 16 + lc, ks, l4);
    if (t + 1 < NT) stageHalf(Bt, K, n0, kN1, Bdst, tid);
    // ---- phase 1 MFMA (aLo x bL)
    __builtin_amdgcn_s_setprio(1);
#pragma unroll
    for (int mi = 0; mi < 4; ++mi)
#pragma unroll
      for (int j = 0; j < 2; ++j)
#pragma unroll
        for (int ks = 0; ks < 2; ++ks)
          acc[mi][j] = __builtin_amdgcn_mfma_f32_16x16x32_bf16(aLo[mi][ks], bL[j][ks], acc[mi][j], 0, 0, 0);
    __builtin_amdgcn_s_setprio(0);
    // ---- issue phase-3 reads (bH); stage B1(t+1); phase 2 MFMA (aHi x bL)
#pragma unroll
    for (int j = 0; j < 2; ++j)
#pragma unroll
      for (int ks = 0; ks < 2; ++ks)
        bH[j][ks] = readFrag128(Bh, rBq + (2 + j) * 16 + lc, ks, l4);
    if (t + 1 < NT) stageHalf(Bt, K, n0 + 128, kN1, Bdst + 8192, tid);
    __builtin_amdgcn_s_setprio(1);
#pragma unroll
    for (int mi = 0; mi < 4; ++mi)
#pragma unroll
      for (int j = 0; j < 2; ++j)
#pragma unroll
        for (int ks = 0; ks < 2; ++ks)
          acc[4 + mi][j] = __builtin_amdgcn_mfma_f32_16x16x32_bf16(aHi[mi][ks], bL[j][ks], acc[4 + mi][j], 0, 0, 0);
    __builtin_amdgcn_s_setprio(0);
    // ---- phase 3: stage A(t+2) into ring slot; MFMA (aLo x bH)
    if (t + 2 < NT) {
      stageHalf(A, K, m0, kN2, Adst, tid);
      stageHalf(A, K, m0 + 128, kN2, Adst + 8192, tid);
    }
    __builtin_amdgcn_s_setprio(1);
#pragma unroll
    for (int mi = 0; mi < 4; ++mi)
#pragma unroll
      for (int j = 0; j < 2; ++j)
#pragma unroll
        for (int ks = 0; ks < 2; ++ks)
          acc[mi][2 + j] = __builtin_amdgcn_mfma_f32_16x16x32_bf16(aLo[mi][ks], bH[j][ks], acc[mi][2 + j], 0, 0, 0);
    __builtin_amdgcn_s_setprio(0);
    // ---- phase 4: MFMA (aHi x bH); counted vmcnt; single end-of-tile barrier
    __builtin_amdgcn_s_setprio(1);
#pragma unroll
    for (int mi = 0; mi < 4; ++mi)
#pragma unroll
      for (int j = 0; j < 2; ++j)
#pragma unroll
        for (int ks = 0; ks < 2; ++ks)
          acc[4 + mi][2 + j] = __builtin_amdgcn_mfma_f32_16x16x32_bf16(aHi[mi][ks], bH[j][ks], acc[4 + mi][2 + j], 0, 0, 0);
    __builtin_amdgcn_s_setprio(0);
    if (t + 2 < NT) asm volatile("s_waitcnt vmcnt(4)" ::: "memory");
    else            asm volatile("s_waitcnt vmcnt(0)" ::: "memory");
    BAR();
    ab = (ab == 2) ? 0 : ab + 1;
  }
  // epilogue
  if constexpr (EPI == 3) {
    u16* swig = reinterpret_cast<u16*>(Cv);
    int scolB = (n0 >> 1) + wn * 32 + lc;
#pragma unroll
    for (int mi = 0; mi < 8; ++mi) {
      int row0 = m0 + wm * 128 + (mi >> 2) * 64 + (mi & 3) * 16 + l4 * 4;
#pragma unroll
      for (int jp = 0; jp < 2; ++jp)
#pragma unroll
        for (int jr = 0; jr < 4; ++jr) {
          float a = acc[mi][jp * 2][jr];
          float b3 = acc[mi][jp * 2 + 1][jr];
          float sv = a / (1.f + __expf(-a)) * b3;
          swig[(size_t)(row0 + jr) * 4096 + scolB + jp * 16] = f2bf(sv);
        }
    }
  } else {
    u16* Cb = reinterpret_cast<u16*>(Cv);
    int colB = n0 + wn * 64 + lc;
#pragma unroll
    for (int mi = 0; mi < 8; ++mi) {
      int row0 = m0 + wm * 128 + (mi >> 2) * 64 + (mi & 3) * 16 + l4 * 4;
#pragma unroll
      for (int j = 0; j < 4; ++j)
#pragma unroll
        for (int jr = 0; jr < 4; ++jr)
          Cb[(size_t)(row0 + jr) * N + colB + j * 16] = f2bf(acc[mi][j][jr]);
    }
  }
}

extern "C" void kernel_launch(void* const* d_in, const int* in_sizes, int n_in,
                              void* d_out, int out_size, void* d_ws, size_t ws_size,
                              hipStream_t stream) {
  const float* x    = (const float*)d_in[0];
  const float* rc   = (const float*)d_in[1];
  const float* rs   = (const float*)d_in[2];
  const float* cond = (const float*)d_in[3];
  const float* wq   = (const float*)d_in[4];
  const float* wk   = (const float*)d_in[5];
  const float* wv   = (const float*)d_in[6];
  const float* wo   = (const float*)d_in[7];
  const float* aaw  = (const float*)d_in[8];
  const float* aab  = (const float*)d_in[9];
  const float* afw  = (const float*)d_in[10];
  const float* afb  = (const float*)d_in[11];
  const float* w1   = (const float*)d_in[12];
  const float* w3   = (const float*)d_in[13];
  const float* w2   = (const float*)d_in[14];
  float* out = (float*)d_out;
  char* ws = (char*)d_ws;

  u16*   wt_qkv = (u16*)  (ws + 0);
  u16*   wt_o   = (u16*)  (ws + 6291456);
  u16*   wt_13  = (u16*)  (ws + 8388608);
  u16*   wt_2   = (u16*)  (ws + 25165824);
  float* modf   = (float*)(ws + 33554432);
  u16*   norm_b = (u16*)  (ws + 33603584);
  u16*   attn_b = (u16*)  (ws + 41992192);
  u16*   qkv_bf = (u16*)  (ws + 50380800);
  float* adpart = (float*)(ws + 50380800);
  float* hbuf   = (float*)(ws + 117489664);
  u16*   swig_b = (u16*)  (ws + 134266880);

  {
    auto f2 = gemm8p<2>; auto f3 = gemm8p<3>;
    hipFuncSetAttribute((const void*)f2, hipFuncAttributeMaxDynamicSharedMemorySize, 163840);
    hipFuncSetAttribute((const void*)f3, hipFuncAttributeMaxDynamicSharedMemorySize, 163840);
  }

  prep_all<<<16768, 256, 0, stream>>>(wq, wk, wv, wo, w1, w3, w2, cond, aaw, afw,
                                      wt_qkv, wt_o, wt_13, wt_2, adpart);
  adaln_reduce<<<dim3(12, 4), 256, 0, stream>>>(adpart, aab, afb, modf);

  ln_mod_kernel<<<4096, 256, 0, stream>>>(x, modf, norm_b);
  gemm8p<2><<<dim3(192), 512, 163840, stream>>>(norm_b, wt_qkv, M_, 3072, 1024, qkv_bf);
  rope_k<<<8192, 256, 0, stream>>>(qkv_bf, rc, rs);
  attn_mfma<<<dim3(32, 16, 2), 256, 0, stream>>>(qkv_bf, rc, rs, attn_b);
  gemm64<<<dim3(8, 64), 256, 0, stream>>>(attn_b, wt_o, M_, 1024, 1024, hbuf, modf + 2048, x);
  ln_mod_kernel<<<4096, 256, 0, stream>>>(hbuf, modf + 6144, norm_b);
  gemm8p<3><<<dim3(512), 512, 163840, stream>>>(norm_b, wt_13, M_, 8192, 1024, swig_b);
  gemm64<<<dim3(8, 64), 256, 0, stream>>>(swig_b, wt_2, M_, 1024, 4096, out, modf + 6144 + 2048, hbuf);
}

// Round 18
// 251.865 us; speedup vs baseline: 1.0426x; 1.0426x over previous
//
#include <hip/hip_runtime.h>

#define DEV __device__ __forceinline__

using bf16x8 = __attribute__((ext_vector_type(8))) short;
using f32x4  = __attribute__((ext_vector_type(4))) float;
using u16 = unsigned short;

constexpr int S_   = 2048;
constexpr int D_   = 1024;
constexpr int M_   = 4096;   // B*S tokens
constexpr int WIN_ = 256;
constexpr float SCALE_ = 0.125f;

typedef const __attribute__((address_space(1))) void* gptr_t;
typedef __attribute__((address_space(3))) void* lptr_t;

DEV u16 f2bf(float f) {
  unsigned u = __builtin_bit_cast(unsigned, f);
  return (u16)((u + 0x7fffu + ((u >> 16) & 1u)) >> 16);
}
DEV float bf2f(u16 b) {
  unsigned u = ((unsigned)b) << 16;
  return __builtin_bit_cast(float, u);
}

// ---------------- merged preprocessing: all weight transposes + adaln partials
__global__ __launch_bounds__(256) void prep_all(const float* __restrict__ wq,
                                                const float* __restrict__ wk,
                                                const float* __restrict__ wv,
                                                const float* __restrict__ wo,
                                                const float* __restrict__ w1,
                                                const float* __restrict__ w3,
                                                const float* __restrict__ w2,
                                                const float* __restrict__ cond,
                                                const float* __restrict__ aaw,
                                                const float* __restrict__ afw,
                                                u16* wt_qkv, u16* wt_o,
                                                u16* wt_13, u16* wt_2,
                                                float* part) {
  __shared__ float tile[32][33];
  __shared__ float sc[128];
  int idx = blockIdx.x;
  int tx = threadIdx.x & 31, ty = threadIdx.x >> 5;
  if (idx < 4096) {
    int z = idx >> 10, t = idx & 1023;
    const float* src; u16* dst;
    switch (z) {
      case 0: src = wq; dst = wt_qkv; break;
      case 1: src = wk; dst = wt_qkv + 1048576; break;
      case 2: src = wv; dst = wt_qkv + 2097152; break;
      default: src = wo; dst = wt_o;
    }
    int n0 = (t & 31) * 32, k0 = (t >> 5) * 32;
#pragma unroll
    for (int p = 0; p < 4; ++p)
      tile[ty + p * 8][tx] = src[(size_t)(k0 + ty + p * 8) * 1024 + n0 + tx];
    __syncthreads();
#pragma unroll
    for (int p = 0; p < 4; ++p)
      dst[(size_t)(n0 + ty + p * 8) * 1024 + k0 + tx] = f2bf(tile[tx][ty + p * 8]);
  } else if (idx < 12288) {
    int i2 = idx - 4096;
    int z = i2 >> 12, t = i2 & 4095;
    const float* src = z ? w3 : w1;
    int add = z ? 16 : 0;
    int n0 = (t & 127) * 32, k0 = (t >> 7) * 32;
#pragma unroll
    for (int p = 0; p < 4; ++p)
      tile[ty + p * 8][tx] = src[(size_t)(k0 + ty + p * 8) * 4096 + n0 + tx];
    __syncthreads();
#pragma unroll
    for (int p = 0; p < 4; ++p) {
      int n = n0 + ty + p * 8;
      int r = ((n >> 4) << 5) + add + (n & 15);
      wt_13[(size_t)r * 1024 + k0 + tx] = f2bf(tile[tx][ty + p * 8]);
    }
  } else if (idx < 16384) {
    int i3 = idx - 12288;
    int n0 = (i3 & 31) * 32, k0 = (i3 >> 5) * 32;
#pragma unroll
    for (int p = 0; p < 4; ++p)
      tile[ty + p * 8][tx] = w2[(size_t)(k0 + ty + p * 8) * 1024 + n0 + tx];
    __syncthreads();
#pragma unroll
    for (int p = 0; p < 4; ++p)
      wt_2[(size_t)(n0 + ty + p * 8) * 4096 + k0 + tx] = f2bf(tile[tx][ty + p * 8]);
  } else {
    int p = idx - 16384;
    int xb = p % 12;
    int rest = p / 12;
    int ks = rest & 7, sb = rest >> 3;
    int b = sb & 1;
    const float* W = (sb & 2) ? afw : aaw;
    if (threadIdx.x < 128) {
      float c = cond[b * 1024 + ks * 128 + threadIdx.x];
      sc[threadIdx.x] = c / (1.f + __expf(-c));
    }
    __syncthreads();
    int n = xb * 256 + threadIdx.x;
    float acc = 0.f;
    const float* Wp = W + (size_t)(ks * 128) * 3072 + n;
#pragma unroll 4
    for (int c = 0; c < 128; ++c) acc += sc[c] * Wp[(size_t)c * 3072];
    part[(size_t)(sb * 8 + ks) * 3072 + n] = acc;
  }
}

__global__ __launch_bounds__(256) void adaln_reduce(const float* __restrict__ part,
                                                    const float* __restrict__ ba,
                                                    const float* __restrict__ bfb,
                                                    float* __restrict__ modout) {
  int n = blockIdx.x * 256 + threadIdx.x;
  int sb = blockIdx.y;
  float acc = ((sb & 2) ? bfb : ba)[n];
#pragma unroll
  for (int k = 0; k < 8; ++k) acc += part[(size_t)(sb * 8 + k) * 3072 + n];
  modout[sb * 3072 + n] = acc;
}

// ---------------- LayerNorm + (1+scale)*x + shift -> bf16
__global__ __launch_bounds__(256) void ln_mod_kernel(const float* __restrict__ x,
                                                     const float* __restrict__ modset,
                                                     u16* __restrict__ out) {
  int m = blockIdx.x;
  int b = m >> 11;
  int tid = threadIdx.x;
  const float4* row = reinterpret_cast<const float4*>(x + (size_t)m * D_);
  float4 v = row[tid];
  float s = v.x + v.y + v.z + v.w;
  float ss = v.x * v.x + v.y * v.y + v.z * v.z + v.w * v.w;
#pragma unroll
  for (int o = 1; o < 64; o <<= 1) { s += __shfl_xor(s, o); ss += __shfl_xor(ss, o); }
  __shared__ float rs[4], rq[4];
  if ((tid & 63) == 0) { rs[tid >> 6] = s; rq[tid >> 6] = ss; }
  __syncthreads();
  s = rs[0] + rs[1] + rs[2] + rs[3];
  ss = rq[0] + rq[1] + rq[2] + rq[3];
  float mu = s * (1.f / D_);
  float rinv = rsqrtf(ss * (1.f / D_) - mu * mu + 1e-5f);
  int n = tid * 4;
  const float* mb = modset + b * 3072;
  float4 sh = *reinterpret_cast<const float4*>(mb + n);
  float4 sc = *reinterpret_cast<const float4*>(mb + 1024 + n);
  ushort4 o4;
  o4.x = f2bf((v.x - mu) * rinv * (1.f + sc.x) + sh.x);
  o4.y = f2bf((v.y - mu) * rinv * (1.f + sc.y) + sh.y);
  o4.z = f2bf((v.z - mu) * rinv * (1.f + sc.z) + sh.z);
  o4.w = f2bf((v.w - mu) * rinv * (1.f + sc.w) + sh.w);
  *reinterpret_cast<ushort4*>(out + (size_t)m * D_ + n) = o4;
}

// ---------------- rotate 4 (even,odd) bf16 pairs
DEV bf16x8 rope8(bf16x8 v, const float* __restrict__ cs, const float* __restrict__ sn,
                 int s, int base) {
  bf16x8 r;
#pragma unroll
  for (int t = 0; t < 4; ++t) {
    float c = cs[s * 32 + base + t], si = sn[s * 32 + base + t];
    float x = bf2f((u16)v[2 * t]), y = bf2f((u16)v[2 * t + 1]);
    r[2 * t] = (short)f2bf(x * c - y * si);
    r[2 * t + 1] = (short)f2bf(x * si + y * c);
  }
  return r;
}

// ---------------- RoPE on K plane only (in-place, once per token)
__global__ __launch_bounds__(256) void rope_k(u16* __restrict__ qkv,
                                              const float* __restrict__ cs,
                                              const float* __restrict__ sn) {
  int idx = blockIdx.x * 256 + threadIdx.x;
  int i = idx & 31;
  int hh = (idx >> 5) & 15;
  int mm = idx >> 9;
  int s = mm & (S_ - 1);
  float c = cs[s * 32 + i], si = sn[s * 32 + i];
  unsigned* kp = reinterpret_cast<unsigned*>(qkv + (size_t)mm * 3072 + 1024 + hh * 64 + 2 * i);
  unsigned kv = *kp;
  float kx = bf2f((u16)(kv & 0xffff)), ky = bf2f((u16)(kv >> 16));
  *kp = (unsigned)f2bf(kx * c - ky * si) | ((unsigned)f2bf(kx * si + ky * c) << 16);
}

// ---------------- MFMA sliding-window flash attention, KVBLK=64 (K pre-roped; Q roped at load)
__global__ __launch_bounds__(256) void attn_mfma(const u16* __restrict__ qkv,
                                                 const float* __restrict__ cs,
                                                 const float* __restrict__ sn,
                                                 u16* __restrict__ out) {
  int q0 = blockIdx.x * 64;
  int h = blockIdx.y, b = blockIdx.z;
  __shared__ __align__(16) u16 Ks[4096];
  __shared__ __align__(16) u16 Vt[4096];
  __shared__ __align__(16) u16 Ps[4][16][72];
  int tid = threadIdx.x, lane = tid & 63, w = tid >> 6;
  int l4 = lane >> 4, lc = lane & 15;
  int sq = q0 + w * 16 + lc;
  const u16* qrow = qkv + (size_t)(b * S_ + sq) * 3072 + h * 64;
  bf16x8 aq0 = rope8(*reinterpret_cast<const bf16x8*>(qrow + l4 * 8), cs, sn, sq, l4 * 4);
  bf16x8 aq1 = rope8(*reinterpret_cast<const bf16x8*>(qrow + 32 + l4 * 8), cs, sn, sq, 16 + l4 * 4);
  int qw0 = q0 + w * 16;
  float mrow[4], lsum[4];
  f32x4 oacc[4];
#pragma unroll
  for (int r = 0; r < 4; ++r) {
    mrow[r] = -__builtin_inff(); lsum[r] = 0.f;
    oacc[r] = f32x4{0.f, 0.f, 0.f, 0.f};
  }
  int kj = lane >> 3;
  int kcb = (lane & 7) * 16;
  int vj = tid & 63;
  int vd0h = (tid >> 6) * 8;
  int jstart = q0 - WIN_; if (jstart < 0) jstart = 0;
  for (int jb = jstart; jb < q0 + 64; jb += 64) {
    __syncthreads();
#pragma unroll
    for (int c = 0; c < 2; ++c) {
      int j = c * 32 + w * 8 + kj;
      const char* src = reinterpret_cast<const char*>(
          qkv + (size_t)(b * S_ + jb + j) * 3072 + 1024 + h * 64) + (kcb ^ ((j & 7) << 4));
      __builtin_amdgcn_global_load_lds((gptr_t)src,
          (lptr_t)(reinterpret_cast<char*>(Ks) + c * 4096 + w * 1024), 16, 0, 0);
    }
#pragma unroll
    for (int half = 0; half < 2; ++half) {
      int dbase = vd0h + half * 32;
      bf16x8 v = *reinterpret_cast<const bf16x8*>(
          qkv + (size_t)(b * S_ + jb + vj) * 3072 + 2048 + h * 64 + dbase);
#pragma unroll
      for (int k2 = 0; k2 < 8; ++k2) {
        int d = dbase + k2;
        int cb = (2 * vj) ^ ((d & 7) << 4);
        *reinterpret_cast<u16*>(reinterpret_cast<char*>(Vt) + d * 128 + cb) = (u16)v[k2];
      }
    }
    __syncthreads();
    if (jb + 63 >= qw0 - WIN_ && jb <= qw0 + 15) {
      f32x4 sacc[4] = {f32x4{0,0,0,0}, f32x4{0,0,0,0}, f32x4{0,0,0,0}, f32x4{0,0,0,0}};
      __builtin_amdgcn_s_setprio(1);
#pragma unroll
      for (int jt = 0; jt < 4; ++jt) {
        int j = jt * 16 + lc;
#pragma unroll
        for (int kh = 0; kh < 2; ++kh) {
          int cbb = (kh * 64 + l4 * 16) ^ ((j & 7) << 4);
          bf16x8 bk = *reinterpret_cast<const bf16x8*>(
              reinterpret_cast<char*>(Ks) + j * 128 + cbb);
          sacc[jt] = __builtin_amdgcn_mfma_f32_16x16x32_bf16(kh == 0 ? aq0 : aq1, bk, sacc[jt], 0, 0, 0);
        }
      }
      __builtin_amdgcn_s_setprio(0);
      float pv[4][4], rr[4];
#pragma unroll
      for (int r = 0; r < 4; ++r) {
        int qa = qw0 + l4 * 4 + r;
        float se[4];
        float cm = -__builtin_inff();
#pragma unroll
        for (int jt = 0; jt < 4; ++jt) {
          int ja = jb + jt * 16 + lc;
          bool val = (ja <= qa) && (qa - ja <= WIN_);
          se[jt] = val ? sacc[jt][r] * SCALE_ : -__builtin_inff();
          cm = fmaxf(cm, se[jt]);
        }
        cm = fmaxf(cm, __shfl_xor(cm, 1));
        cm = fmaxf(cm, __shfl_xor(cm, 2));
        cm = fmaxf(cm, __shfl_xor(cm, 4));
        cm = fmaxf(cm, __shfl_xor(cm, 8));
        float mnew = fmaxf(mrow[r], cm);
        float esum = 0.f;
#pragma unroll
        for (int jt = 0; jt < 4; ++jt) {
          float e = __expf(se[jt] - mnew);
          e = (se[jt] == -__builtin_inff()) ? 0.f : e;
          pv[jt][r] = e;
          esum += e;
        }
        esum += __shfl_xor(esum, 1);
        esum += __shfl_xor(esum, 2);
        esum += __shfl_xor(esum, 4);
        esum += __shfl_xor(esum, 8);
        float rf = __expf(mrow[r] - mnew);
        rf = (mnew == -__builtin_inff()) ? 0.f : rf;
        rr[r] = rf;
        lsum[r] = lsum[r] * rf + esum;
        mrow[r] = mnew;
      }
#pragma unroll
      for (int jt = 0; jt < 4; ++jt)
#pragma unroll
        for (int r = 0; r < 4; ++r)
          Ps[w][l4 * 4 + r][jt * 16 + lc] = f2bf(pv[jt][r]);
      asm volatile("s_waitcnt lgkmcnt(0)" ::: "memory");
      __builtin_amdgcn_sched_barrier(0);
      bf16x8 ap[2];
#pragma unroll
      for (int js = 0; js < 2; ++js)
        ap[js] = *reinterpret_cast<const bf16x8*>(&Ps[w][lc][js * 32 + l4 * 8]);
      __builtin_amdgcn_s_setprio(1);
#pragma unroll
      for (int dt = 0; dt < 4; ++dt) {
        int d = dt * 16 + lc;
#pragma unroll
        for (int r = 0; r < 4; ++r) oacc[dt][r] *= rr[r];
#pragma unroll
        for (int js = 0; js < 2; ++js) {
          int cb = (js * 64 + l4 * 16) ^ ((d & 7) << 4);
          bf16x8 bv = *reinterpret_cast<const bf16x8*>(
              reinterpret_cast<char*>(Vt) + d * 128 + cb);
          oacc[dt] = __builtin_amdgcn_mfma_f32_16x16x32_bf16(ap[js], bv, oacc[dt], 0, 0, 0);
        }
      }
      __builtin_amdgcn_s_setprio(0);
    }
  }
  float inv[4];
#pragma unroll
  for (int r = 0; r < 4; ++r) inv[r] = 1.f / lsum[r];
  size_t obase = (size_t)(b * S_ + qw0) * D_ + h * 64;
#pragma unroll
  for (int dt = 0; dt < 4; ++dt)
#pragma unroll
    for (int r = 0; r < 4; ++r)
      out[obase + (size_t)(l4 * 4 + r) * D_ + dt * 16 + lc] = f2bf(oacc[dt][r] * inv[r]);
}

// ---------------- shared fragment helpers for BK=32 tiles (row stride 64 B)
DEV bf16x8 read_frag(const u16* tile, int r16, int lane) {
  int r = r16 + (lane & 15);
  int cb = ((lane >> 4) << 4) ^ (((r >> 1) & 3) << 4);
  return *reinterpret_cast<const bf16x8*>(reinterpret_cast<const char*>(tile) + r * 64 + cb);
}

DEV void stage_tile(const u16* __restrict__ src, int ld, int rowBase, int kBase,
                    u16* tile, int tid) {
#pragma unroll
  for (int c = 0; c < 2; ++c) {
    int row = c * 64 + (tid >> 2);
    int cbs = ((tid & 3) << 4) ^ (((row >> 1) & 3) << 4);
    const char* g = reinterpret_cast<const char*>(src + (size_t)(rowBase + row) * ld + kBase) + cbs;
    char* l = reinterpret_cast<char*>(tile) + c * 4096 + (tid >> 6) * 1024;
    __builtin_amdgcn_global_load_lds((gptr_t)g, (lptr_t)l, 16, 0, 0);
  }
}

DEV void stage64(const u16* __restrict__ src, int ld, int rowBase, int kBase,
                 u16* tile, int tid) {
  int row = tid >> 2;
  int cbs = ((tid & 3) << 4) ^ (((row >> 1) & 3) << 4);
  const char* g = reinterpret_cast<const char*>(src + (size_t)(rowBase + row) * ld + kBase) + cbs;
  char* l = reinterpret_cast<char*>(tile) + (tid >> 6) * 1024;
  __builtin_amdgcn_global_load_lds((gptr_t)g, (lptr_t)l, 16, 0, 0);
}

#define BAR()   asm volatile("s_barrier" ::: "memory")

// ---------------- 64x128 gemm, 4-deep pipelined, counted vmcnt (3 loads/tile)
__global__ __launch_bounds__(256, 2) void gemm64(const u16* __restrict__ A,
                                                 const u16* __restrict__ Bt,
                                                 int M, int N, int K,
                                                 float* __restrict__ Cv,
                                                 const float* __restrict__ gate,
                                                 const float* __restrict__ resid) {
  __shared__ __align__(16) u16 ldsA[4][2048];
  __shared__ __align__(16) u16 ldsB[4][4096];
  int tid = threadIdx.x;
  int lane = tid & 63;
  int w = tid >> 6;
  int wr = w >> 1, wc = w & 1;
  int m0 = blockIdx.y * 64;
  int n0 = blockIdx.x * 128;
  f32x4 zero = {0.f, 0.f, 0.f, 0.f};
  f32x4 acc[2][4];
#pragma unroll
  for (int i = 0; i < 2; ++i)
#pragma unroll
    for (int j = 0; j < 4; ++j) acc[i][j] = zero;
  int nt = K >> 5;
#pragma unroll
  for (int p = 0; p < 3; ++p) {
    stage64(A, K, m0, p << 5, &ldsA[p][0], tid);
    stage_tile(Bt, K, n0, p << 5, &ldsB[p][0], tid);
  }
  asm volatile("s_waitcnt vmcnt(6)" ::: "memory");
  BAR();
  for (int t = 0; t < nt; ++t) {
    bf16x8 af[2], bfr[4];
#pragma unroll
    for (int i = 0; i < 2; ++i) af[i] = read_frag(&ldsA[t & 3][0], wr * 32 + i * 16, lane);
#pragma unroll
    for (int i = 0; i < 4; ++i) bfr[i] = read_frag(&ldsB[t & 3][0], wc * 64 + i * 16, lane);
    if (t + 3 < nt) {
      stage64(A, K, m0, (t + 3) << 5, &ldsA[(t + 3) & 3][0], tid);
      stage_tile(Bt, K, n0, (t + 3) << 5, &ldsB[(t + 3) & 3][0], tid);
    }
    __builtin_amdgcn_s_setprio(1);
#pragma unroll
    for (int i = 0; i < 2; ++i)
#pragma unroll
      for (int j = 0; j < 4; ++j)
        acc[i][j] = __builtin_amdgcn_mfma_f32_16x16x32_bf16(af[i], bfr[j], acc[i][j], 0, 0, 0);
    __builtin_amdgcn_s_setprio(0);
    if (t + 3 < nt)      asm volatile("s_waitcnt vmcnt(6)" ::: "memory");
    else if (t + 2 < nt) asm volatile("s_waitcnt vmcnt(3)" ::: "memory");
    else                 asm volatile("s_waitcnt vmcnt(0)" ::: "memory");
    BAR();
  }
  int rowB = m0 + wr * 32 + ((lane >> 4) << 2);
  int colB = n0 + wc * 64 + (lane & 15);
#pragma unroll
  for (int i = 0; i < 2; ++i) {
#pragma unroll
    for (int j = 0; j < 4; ++j) {
      int col = colB + j * 16;
#pragma unroll
      for (int jr = 0; jr < 4; ++jr) {
        int row = rowB + i * 16 + jr;
        float v = acc[i][j][jr];
        size_t idx = (size_t)row * N + col;
        int bb = row >> 11;
        Cv[idx] = resid[idx] + gate[bb * 3072 + col] * v;
      }
    }
  }
}

// ================== 256x256 GEMM, BK=64, A 3-ring, 1 barrier/tile (R16-proven) ==================
DEV bf16x8 readFrag128(const u16* halfBase, int rowInHalf, int ks, int l4) {
  int cb = ((ks << 6) + (l4 << 4)) ^ ((rowInHalf & 7) << 4);
  return *reinterpret_cast<const bf16x8*>(
      reinterpret_cast<const char*>(halfBase) + rowInHalf * 128 + cb);
}

DEV void stageHalf(const u16* __restrict__ src, int ld, int rowBase, int kBase,
                   u16* halfBase, int tid) {
#pragma unroll
  for (int c = 0; c < 2; ++c) {
    int row = c * 64 + (tid >> 3);
    int cbs = (((tid & 7) ^ ((tid >> 3) & 7)) << 4);
    const char* g = reinterpret_cast<const char*>(src + (size_t)(rowBase + row) * ld + kBase) + cbs;
    char* l = reinterpret_cast<char*>(halfBase) + c * 8192 + (tid >> 6) * 1024;
    __builtin_amdgcn_global_load_lds((gptr_t)g, (lptr_t)l, 16, 0, 0);
  }
}

// EPI 2: bf16 store | EPI 3: fused swiglu on 16-col-interleaved B layout
template <int EPI>
__global__ __launch_bounds__(512, 1) void gemm8p(const u16* __restrict__ A,
                                                 const u16* __restrict__ Bt,
                                                 int M, int N, int K,
                                                 void* __restrict__ Cv) {
  extern __shared__ __align__(16) u16 smem[];
  u16* Abase = smem;            // 3 bufs x 16 KiB = 96 KiB
  u16* Bbase = smem + 49152;    // 2 bufs x 16 KiB = 64 KiB
  int tid = threadIdx.x, lane = tid & 63, w = tid >> 6;
  int wm = w >> 2, wn = w & 3;
  int l4 = lane >> 4, lc = lane & 15;
  int wg = ((int)blockIdx.x & 7) * ((int)gridDim.x >> 3) + ((int)blockIdx.x >> 3);
  int nby = M >> 8;
  int bx = wg / nby, by = wg % nby;
  int m0 = by << 8, n0 = bx << 8;
  int NT = K >> 6;
  f32x4 zero = {0.f, 0.f, 0.f, 0.f};
  f32x4 acc[8][4];
#pragma unroll
  for (int i = 0; i < 8; ++i)
#pragma unroll
    for (int j = 0; j < 4; ++j) acc[i][j] = zero;
  stageHalf(A, K, m0, 0, Abase, tid);
  stageHalf(A, K, m0 + 128, 0, Abase + 8192, tid);
  stageHalf(Bt, K, n0, 0, Bbase, tid);
  stageHalf(Bt, K, n0 + 128, 0, Bbase + 8192, tid);
  stageHalf(A, K, m0, 64, Abase + 16384, tid);
  stageHalf(A, K, m0 + 128, 64, Abase + 16384 + 8192, tid);
  asm volatile("s_waitcnt vmcnt(4)" ::: "memory");
  BAR();
  int rBq = (wn & 1) * 64;
  int ab = 0;   // t % 3
  for (int t = 0; t < NT; ++t) {
    const u16* Ah = Abase + ab * 16384 + wm * 8192;
    const u16* Bh = Bbase + (t & 1) * 16384 + (wn >> 1) * 8192;
    u16* Bdst = Bbase + ((t + 1) & 1) * 16384;
    int ad = ab + 2; if (ad >= 3) ad -= 3;
    u16* Adst = Abase + ad * 16384;
    int kN1 = (t + 1) << 6, kN2 = (t + 2) << 6;
    bf16x8 aLo[4][2], aHi[4][2], bFr[2][2];
    // ---- phase 1: read A-lo + B-lo; stage B0(t+1); MFMA Q(lo,lo)
#pragma unroll
    for (int mi = 0; mi < 4; ++mi)
#pragma unroll
      for (int ks = 0; ks < 2; ++ks)
        aLo[mi][ks] = readFrag128(Ah, mi * 16 + lc, ks, l4);
#pragma unroll
    for (int j = 0; j < 2; ++j)
#pragma unroll
      for (int ks = 0; ks < 2; ++ks)
        bFr[j][ks] = readFrag128(Bh, rBq + j * 16 + lc, ks, l4);
    if (t + 1 < NT) stageHalf(Bt, K, n0, kN1, Bdst, tid);
    __builtin_amdgcn_s_setprio(1);
#pragma unroll
    for (int mi = 0; mi < 4; ++mi)
#pragma unroll
      for (int j = 0; j < 2; ++j)
#pragma unroll
        for (int ks = 0; ks < 2; ++ks)
          acc[mi][j] = __builtin_amdgcn_mfma_f32_16x16x32_bf16(aLo[mi][ks], bFr[j][ks], acc[mi][j], 0, 0, 0);
    __builtin_amdgcn_s_setprio(0);
    // ---- phase 2: read A-hi; stage B1(t+1); MFMA Q(hi,lo)
#pragma unroll
    for (int mi = 0; mi < 4; ++mi)
#pragma unroll
      for (int ks = 0; ks < 2; ++ks)
        aHi[mi][ks] = readFrag128(Ah, 64 + mi * 16 + lc, ks, l4);
    if (t + 1 < NT) stageHalf(Bt, K, n0 + 128, kN1, Bdst + 8192, tid);
    __builtin_amdgcn_s_setprio(1);
#pragma unroll
    for (int mi = 0; mi < 4; ++mi)
#pragma unroll
      for (int j = 0; j < 2; ++j)
#pragma unroll
        for (int ks = 0; ks < 2; ++ks)
          acc[4 + mi][j] = __builtin_amdgcn_mfma_f32_16x16x32_bf16(aHi[mi][ks], bFr[j][ks], acc[4 + mi][j], 0, 0, 0);
    __builtin_amdgcn_s_setprio(0);
    // ---- phase 3: read B-hi; stage A(t+2) into ring slot
#pragma unroll
    for (int j = 0; j < 2; ++j)
#pragma unroll
      for (int ks = 0; ks < 2; ++ks)
        bFr[j][ks] = readFrag128(Bh, rBq + (2 + j) * 16 + lc, ks, l4);
    if (t + 2 < NT) {
      stageHalf(A, K, m0, kN2, Adst, tid);
      stageHalf(A, K, m0 + 128, kN2, Adst + 8192, tid);
    }
    __builtin_amdgcn_s_setprio(1);
#pragma unroll
    for (int mi = 0; mi < 4; ++mi)
#pragma unroll
      for (int j = 0; j < 2; ++j)
#pragma unroll
        for (int ks = 0; ks < 2; ++ks)
          acc[mi][2 + j] = __builtin_amdgcn_mfma_f32_16x16x32_bf16(aLo[mi][ks], bFr[j][ks], acc[mi][2 + j], 0, 0, 0);
    __builtin_amdgcn_s_setprio(0);
    // ---- phase 4: MFMA Q(hi,hi); counted vmcnt; single end-of-tile barrier
    __builtin_amdgcn_s_setprio(1);
#pragma unroll
    for (int mi = 0; mi < 4; ++mi)
#pragma unroll
      for (int j = 0; j < 2; ++j)
#pragma unroll
        for (int ks = 0; ks < 2; ++ks)
          acc[4 + mi][2 + j] = __builtin_amdgcn_mfma_f32_16x16x32_bf16(aHi[mi][ks], bFr[j][ks], acc[4 + mi][2 + j], 0, 0, 0);
    __builtin_amdgcn_s_setprio(0);
    if (t + 2 < NT) asm volatile("s_waitcnt vmcnt(4)" ::: "memory");
    else            asm volatile("s_waitcnt vmcnt(0)" ::: "memory");
    BAR();
    ab = (ab == 2) ? 0 : ab + 1;
  }
  // epilogue
  if constexpr (EPI == 3) {
    u16* swig = reinterpret_cast<u16*>(Cv);
    int scolB = (n0 >> 1) + wn * 32 + lc;
#pragma unroll
    for (int mi = 0; mi < 8; ++mi) {
      int row0 = m0 + wm * 128 + (mi >> 2) * 64 + (mi & 3) * 16 + l4 * 4;
#pragma unroll
      for (int jp = 0; jp < 2; ++jp)
#pragma unroll
        for (int jr = 0; jr < 4; ++jr) {
          float a = acc[mi][jp * 2][jr];
          float b3 = acc[mi][jp * 2 + 1][jr];
          float sv = a / (1.f + __expf(-a)) * b3;
          swig[(size_t)(row0 + jr) * 4096 + scolB + jp * 16] = f2bf(sv);
        }
    }
  } else {
    u16* Cb = reinterpret_cast<u16*>(Cv);
    int colB = n0 + wn * 64 + lc;
#pragma unroll
    for (int mi = 0; mi < 8; ++mi) {
      int row0 = m0 + wm * 128 + (mi >> 2) * 64 + (mi & 3) * 16 + l4 * 4;
#pragma unroll
      for (int j = 0; j < 4; ++j)
#pragma unroll
        for (int jr = 0; jr < 4; ++jr)
          Cb[(size_t)(row0 + jr) * N + colB + j * 16] = f2bf(acc[mi][j][jr]);
    }
  }
}

extern "C" void kernel_launch(void* const* d_in, const int* in_sizes, int n_in,
                              void* d_out, int out_size, void* d_ws, size_t ws_size,
                              hipStream_t stream) {
  const float* x    = (const float*)d_in[0];
  const float* rc   = (const float*)d_in[1];
  const float* rs   = (const float*)d_in[2];
  const float* cond = (const float*)d_in[3];
  const float* wq   = (const float*)d_in[4];
  const float* wk   = (const float*)d_in[5];
  const float* wv   = (const float*)d_in[6];
  const float* wo   = (const float*)d_in[7];
  const float* aaw  = (const float*)d_in[8];
  const float* aab  = (const float*)d_in[9];
  const float* afw  = (const float*)d_in[10];
  const float* afb  = (const float*)d_in[11];
  const float* w1   = (const float*)d_in[12];
  const float* w3   = (const float*)d_in[13];
  const float* w2   = (const float*)d_in[14];
  float* out = (float*)d_out;
  char* ws = (char*)d_ws;

  u16*   wt_qkv = (u16*)  (ws + 0);
  u16*   wt_o   = (u16*)  (ws + 6291456);
  u16*   wt_13  = (u16*)  (ws + 8388608);
  u16*   wt_2   = (u16*)  (ws + 25165824);
  float* modf   = (float*)(ws + 33554432);
  u16*   norm_b = (u16*)  (ws + 33603584);
  u16*   attn_b = (u16*)  (ws + 41992192);
  u16*   qkv_bf = (u16*)  (ws + 50380800);
  float* adpart = (float*)(ws + 50380800);
  float* hbuf   = (float*)(ws + 117489664);
  u16*   swig_b = (u16*)  (ws + 134266880);

  {
    auto f2 = gemm8p<2>; auto f3 = gemm8p<3>;
    hipFuncSetAttribute((const void*)f2, hipFuncAttributeMaxDynamicSharedMemorySize, 163840);
    hipFuncSetAttribute((const void*)f3, hipFuncAttributeMaxDynamicSharedMemorySize, 163840);
  }

  prep_all<<<16768, 256, 0, stream>>>(wq, wk, wv, wo, w1, w3, w2, cond, aaw, afw,
                                      wt_qkv, wt_o, wt_13, wt_2, adpart);
  adaln_reduce<<<dim3(12, 4), 256, 0, stream>>>(adpart, aab, afb, modf);

  ln_mod_kernel<<<4096, 256, 0, stream>>>(x, modf, norm_b);
  gemm8p<2><<<dim3(192), 512, 163840, stream>>>(norm_b, wt_qkv, M_, 3072, 1024, qkv_bf);
  rope_k<<<8192, 256, 0, stream>>>(qkv_bf, rc, rs);
  attn_mfma<<<dim3(32, 16, 2), 256, 0, stream>>>(qkv_bf, rc, rs, attn_b);
  gemm64<<<dim3(8, 64), 256, 0, stream>>>(attn_b, wt_o, M_, 1024, 1024, hbuf, modf + 2048, x);
  ln_mod_kernel<<<4096, 256, 0, stream>>>(hbuf, modf + 6144, norm_b);
  gemm8p<3><<<dim3(512), 512, 163840, stream>>>(norm_b, wt_13, M_, 8192, 1024, swig_b);
  gemm64<<<dim3(8, 64), 256, 0, stream>>>(swig_b, wt_2, M_, 1024, 4096, out, modf + 6144 + 2048, hbuf);
}

// Round 19
// 251.246 us; speedup vs baseline: 1.0452x; 1.0025x over previous
//
#include <hip/hip_runtime.h>

#define DEV __device__ __forceinline__

using bf16x8 = __attribute__((ext_vector_type(8))) short;
using f32x4  = __attribute__((ext_vector_type(4))) float;
using u16 = unsigned short;

constexpr int S_   = 2048;
constexpr int D_   = 1024;
constexpr int M_   = 4096;   // B*S tokens
constexpr int WIN_ = 256;
constexpr float SCALE_ = 0.125f;

typedef const __attribute__((address_space(1))) void* gptr_t;
typedef __attribute__((address_space(3))) void* lptr_t;

DEV u16 f2bf(float f) {
  unsigned u = __builtin_bit_cast(unsigned, f);
  return (u16)((u + 0x7fffu + ((u >> 16) & 1u)) >> 16);
}
DEV float bf2f(u16 b) {
  unsigned u = ((unsigned)b) << 16;
  return __builtin_bit_cast(float, u);
}

// ---------------- merged preprocessing: all weight transposes + adaln partials
__global__ __launch_bounds__(256) void prep_all(const float* __restrict__ wq,
                                                const float* __restrict__ wk,
                                                const float* __restrict__ wv,
                                                const float* __restrict__ wo,
                                                const float* __restrict__ w1,
                                                const float* __restrict__ w3,
                                                const float* __restrict__ w2,
                                                const float* __restrict__ cond,
                                                const float* __restrict__ aaw,
                                                const float* __restrict__ afw,
                                                u16* wt_qkv, u16* wt_o,
                                                u16* wt_13, u16* wt_2,
                                                float* part) {
  __shared__ float tile[32][33];
  __shared__ float sc[128];
  int idx = blockIdx.x;
  int tx = threadIdx.x & 31, ty = threadIdx.x >> 5;
  if (idx < 4096) {
    int z = idx >> 10, t = idx & 1023;
    const float* src; u16* dst;
    switch (z) {
      case 0: src = wq; dst = wt_qkv; break;
      case 1: src = wk; dst = wt_qkv + 1048576; break;
      case 2: src = wv; dst = wt_qkv + 2097152; break;
      default: src = wo; dst = wt_o;
    }
    int n0 = (t & 31) * 32, k0 = (t >> 5) * 32;
#pragma unroll
    for (int p = 0; p < 4; ++p)
      tile[ty + p * 8][tx] = src[(size_t)(k0 + ty + p * 8) * 1024 + n0 + tx];
    __syncthreads();
#pragma unroll
    for (int p = 0; p < 4; ++p)
      dst[(size_t)(n0 + ty + p * 8) * 1024 + k0 + tx] = f2bf(tile[tx][ty + p * 8]);
  } else if (idx < 12288) {
    int i2 = idx - 4096;
    int z = i2 >> 12, t = i2 & 4095;
    const float* src = z ? w3 : w1;
    int add = z ? 16 : 0;
    int n0 = (t & 127) * 32, k0 = (t >> 7) * 32;
#pragma unroll
    for (int p = 0; p < 4; ++p)
      tile[ty + p * 8][tx] = src[(size_t)(k0 + ty + p * 8) * 4096 + n0 + tx];
    __syncthreads();
#pragma unroll
    for (int p = 0; p < 4; ++p) {
      int n = n0 + ty + p * 8;
      int r = ((n >> 4) << 5) + add + (n & 15);
      wt_13[(size_t)r * 1024 + k0 + tx] = f2bf(tile[tx][ty + p * 8]);
    }
  } else if (idx < 16384) {
    int i3 = idx - 12288;
    int n0 = (i3 & 31) * 32, k0 = (i3 >> 5) * 32;
#pragma unroll
    for (int p = 0; p < 4; ++p)
      tile[ty + p * 8][tx] = w2[(size_t)(k0 + ty + p * 8) * 1024 + n0 + tx];
    __syncthreads();
#pragma unroll
    for (int p = 0; p < 4; ++p)
      wt_2[(size_t)(n0 + ty + p * 8) * 4096 + k0 + tx] = f2bf(tile[tx][ty + p * 8]);
  } else {
    int p = idx - 16384;
    int xb = p % 12;
    int rest = p / 12;
    int ks = rest & 7, sb = rest >> 3;
    int b = sb & 1;
    const float* W = (sb & 2) ? afw : aaw;
    if (threadIdx.x < 128) {
      float c = cond[b * 1024 + ks * 128 + threadIdx.x];
      sc[threadIdx.x] = c / (1.f + __expf(-c));
    }
    __syncthreads();
    int n = xb * 256 + threadIdx.x;
    float acc = 0.f;
    const float* Wp = W + (size_t)(ks * 128) * 3072 + n;
#pragma unroll 4
    for (int c = 0; c < 128; ++c) acc += sc[c] * Wp[(size_t)c * 3072];
    part[(size_t)(sb * 8 + ks) * 3072 + n] = acc;
  }
}

__global__ __launch_bounds__(256) void adaln_reduce(const float* __restrict__ part,
                                                    const float* __restrict__ ba,
                                                    const float* __restrict__ bfb,
                                                    float* __restrict__ modout) {
  int n = blockIdx.x * 256 + threadIdx.x;
  int sb = blockIdx.y;
  float acc = ((sb & 2) ? bfb : ba)[n];
#pragma unroll
  for (int k = 0; k < 8; ++k) acc += part[(size_t)(sb * 8 + k) * 3072 + n];
  modout[sb * 3072 + n] = acc;
}

// ---------------- LayerNorm + (1+scale)*x + shift -> bf16
__global__ __launch_bounds__(256) void ln_mod_kernel(const float* __restrict__ x,
                                                     const float* __restrict__ modset,
                                                     u16* __restrict__ out) {
  int m = blockIdx.x;
  int b = m >> 11;
  int tid = threadIdx.x;
  const float4* row = reinterpret_cast<const float4*>(x + (size_t)m * D_);
  float4 v = row[tid];
  float s = v.x + v.y + v.z + v.w;
  float ss = v.x * v.x + v.y * v.y + v.z * v.z + v.w * v.w;
#pragma unroll
  for (int o = 1; o < 64; o <<= 1) { s += __shfl_xor(s, o); ss += __shfl_xor(ss, o); }
  __shared__ float rs[4], rq[4];
  if ((tid & 63) == 0) { rs[tid >> 6] = s; rq[tid >> 6] = ss; }
  __syncthreads();
  s = rs[0] + rs[1] + rs[2] + rs[3];
  ss = rq[0] + rq[1] + rq[2] + rq[3];
  float mu = s * (1.f / D_);
  float rinv = rsqrtf(ss * (1.f / D_) - mu * mu + 1e-5f);
  int n = tid * 4;
  const float* mb = modset + b * 3072;
  float4 sh = *reinterpret_cast<const float4*>(mb + n);
  float4 sc = *reinterpret_cast<const float4*>(mb + 1024 + n);
  ushort4 o4;
  o4.x = f2bf((v.x - mu) * rinv * (1.f + sc.x) + sh.x);
  o4.y = f2bf((v.y - mu) * rinv * (1.f + sc.y) + sh.y);
  o4.z = f2bf((v.z - mu) * rinv * (1.f + sc.z) + sh.z);
  o4.w = f2bf((v.w - mu) * rinv * (1.f + sc.w) + sh.w);
  *reinterpret_cast<ushort4*>(out + (size_t)m * D_ + n) = o4;
}

// ---------------- rotate 4 (even,odd) bf16 pairs
DEV bf16x8 rope8(bf16x8 v, const float* __restrict__ cs, const float* __restrict__ sn,
                 int s, int base) {
  bf16x8 r;
#pragma unroll
  for (int t = 0; t < 4; ++t) {
    float c = cs[s * 32 + base + t], si = sn[s * 32 + base + t];
    float x = bf2f((u16)v[2 * t]), y = bf2f((u16)v[2 * t + 1]);
    r[2 * t] = (short)f2bf(x * c - y * si);
    r[2 * t + 1] = (short)f2bf(x * si + y * c);
  }
  return r;
}

// ---------------- RoPE on K plane only (in-place, once per token)
__global__ __launch_bounds__(256) void rope_k(u16* __restrict__ qkv,
                                              const float* __restrict__ cs,
                                              const float* __restrict__ sn) {
  int idx = blockIdx.x * 256 + threadIdx.x;
  int i = idx & 31;
  int hh = (idx >> 5) & 15;
  int mm = idx >> 9;
  int s = mm & (S_ - 1);
  float c = cs[s * 32 + i], si = sn[s * 32 + i];
  unsigned* kp = reinterpret_cast<unsigned*>(qkv + (size_t)mm * 3072 + 1024 + hh * 64 + 2 * i);
  unsigned kv = *kp;
  float kx = bf2f((u16)(kv & 0xffff)), ky = bf2f((u16)(kv >> 16));
  *kp = (unsigned)f2bf(kx * c - ky * si) | ((unsigned)f2bf(kx * si + ky * c) << 16);
}

// ---------------- MFMA sliding-window flash attention, KVBLK=64 (K pre-roped; Q roped at load)
// q-block index XCD-swizzled: each XCD gets 4 consecutive q-blocks per (h,b) for KV L2 reuse.
__global__ __launch_bounds__(256) void attn_mfma(const u16* __restrict__ qkv,
                                                 const float* __restrict__ cs,
                                                 const float* __restrict__ sn,
                                                 u16* __restrict__ out) {
  int qb = (int)blockIdx.x;
  int qbe = (qb & 7) * 4 + (qb >> 3);        // bijective: XCD k owns q-blocks 4k..4k+3
  int q0 = qbe * 64;
  int h = blockIdx.y, b = blockIdx.z;
  __shared__ __align__(16) u16 Ks[4096];
  __shared__ __align__(16) u16 Vt[4096];
  __shared__ __align__(16) u16 Ps[4][16][72];
  int tid = threadIdx.x, lane = tid & 63, w = tid >> 6;
  int l4 = lane >> 4, lc = lane & 15;
  int sq = q0 + w * 16 + lc;
  const u16* qrow = qkv + (size_t)(b * S_ + sq) * 3072 + h * 64;
  bf16x8 aq0 = rope8(*reinterpret_cast<const bf16x8*>(qrow + l4 * 8), cs, sn, sq, l4 * 4);
  bf16x8 aq1 = rope8(*reinterpret_cast<const bf16x8*>(qrow + 32 + l4 * 8), cs, sn, sq, 16 + l4 * 4);
  int qw0 = q0 + w * 16;
  float mrow[4], lsum[4];
  f32x4 oacc[4];
#pragma unroll
  for (int r = 0; r < 4; ++r) {
    mrow[r] = -__builtin_inff(); lsum[r] = 0.f;
    oacc[r] = f32x4{0.f, 0.f, 0.f, 0.f};
  }
  int kj = lane >> 3;
  int kcb = (lane & 7) * 16;
  int vj = tid & 63;
  int vd0h = (tid >> 6) * 8;
  int jstart = q0 - WIN_; if (jstart < 0) jstart = 0;
  for (int jb = jstart; jb < q0 + 64; jb += 64) {
    __syncthreads();
#pragma unroll
    for (int c = 0; c < 2; ++c) {
      int j = c * 32 + w * 8 + kj;
      const char* src = reinterpret_cast<const char*>(
          qkv + (size_t)(b * S_ + jb + j) * 3072 + 1024 + h * 64) + (kcb ^ ((j & 7) << 4));
      __builtin_amdgcn_global_load_lds((gptr_t)src,
          (lptr_t)(reinterpret_cast<char*>(Ks) + c * 4096 + w * 1024), 16, 0, 0);
    }
#pragma unroll
    for (int half = 0; half < 2; ++half) {
      int dbase = vd0h + half * 32;
      bf16x8 v = *reinterpret_cast<const bf16x8*>(
          qkv + (size_t)(b * S_ + jb + vj) * 3072 + 2048 + h * 64 + dbase);
#pragma unroll
      for (int k2 = 0; k2 < 8; ++k2) {
        int d = dbase + k2;
        int cb = (2 * vj) ^ ((d & 7) << 4);
        *reinterpret_cast<u16*>(reinterpret_cast<char*>(Vt) + d * 128 + cb) = (u16)v[k2];
      }
    }
    __syncthreads();
    if (jb + 63 >= qw0 - WIN_ && jb <= qw0 + 15) {
      f32x4 sacc[4] = {f32x4{0,0,0,0}, f32x4{0,0,0,0}, f32x4{0,0,0,0}, f32x4{0,0,0,0}};
      __builtin_amdgcn_s_setprio(1);
#pragma unroll
      for (int jt = 0; jt < 4; ++jt) {
        int j = jt * 16 + lc;
#pragma unroll
        for (int kh = 0; kh < 2; ++kh) {
          int cbb = (kh * 64 + l4 * 16) ^ ((j & 7) << 4);
          bf16x8 bk = *reinterpret_cast<const bf16x8*>(
              reinterpret_cast<char*>(Ks) + j * 128 + cbb);
          sacc[jt] = __builtin_amdgcn_mfma_f32_16x16x32_bf16(kh == 0 ? aq0 : aq1, bk, sacc[jt], 0, 0, 0);
        }
      }
      __builtin_amdgcn_s_setprio(0);
      float pv[4][4], rr[4];
#pragma unroll
      for (int r = 0; r < 4; ++r) {
        int qa = qw0 + l4 * 4 + r;
        float se[4];
        float cm = -__builtin_inff();
#pragma unroll
        for (int jt = 0; jt < 4; ++jt) {
          int ja = jb + jt * 16 + lc;
          bool val = (ja <= qa) && (qa - ja <= WIN_);
          se[jt] = val ? sacc[jt][r] * SCALE_ : -__builtin_inff();
          cm = fmaxf(cm, se[jt]);
        }
        cm = fmaxf(cm, __shfl_xor(cm, 1));
        cm = fmaxf(cm, __shfl_xor(cm, 2));
        cm = fmaxf(cm, __shfl_xor(cm, 4));
        cm = fmaxf(cm, __shfl_xor(cm, 8));
        float mnew = fmaxf(mrow[r], cm);
        float esum = 0.f;
#pragma unroll
        for (int jt = 0; jt < 4; ++jt) {
          float e = __expf(se[jt] - mnew);
          e = (se[jt] == -__builtin_inff()) ? 0.f : e;
          pv[jt][r] = e;
          esum += e;
        }
        esum += __shfl_xor(esum, 1);
        esum += __shfl_xor(esum, 2);
        esum += __shfl_xor(esum, 4);
        esum += __shfl_xor(esum, 8);
        float rf = __expf(mrow[r] - mnew);
        rf = (mnew == -__builtin_inff()) ? 0.f : rf;
        rr[r] = rf;
        lsum[r] = lsum[r] * rf + esum;
        mrow[r] = mnew;
      }
#pragma unroll
      for (int jt = 0; jt < 4; ++jt)
#pragma unroll
        for (int r = 0; r < 4; ++r)
          Ps[w][l4 * 4 + r][jt * 16 + lc] = f2bf(pv[jt][r]);
      asm volatile("s_waitcnt lgkmcnt(0)" ::: "memory");
      __builtin_amdgcn_sched_barrier(0);
      bf16x8 ap[2];
#pragma unroll
      for (int js = 0; js < 2; ++js)
        ap[js] = *reinterpret_cast<const bf16x8*>(&Ps[w][lc][js * 32 + l4 * 8]);
      __builtin_amdgcn_s_setprio(1);
#pragma unroll
      for (int dt = 0; dt < 4; ++dt) {
        int d = dt * 16 + lc;
#pragma unroll
        for (int r = 0; r < 4; ++r) oacc[dt][r] *= rr[r];
#pragma unroll
        for (int js = 0; js < 2; ++js) {
          int cb = (js * 64 + l4 * 16) ^ ((d & 7) << 4);
          bf16x8 bv = *reinterpret_cast<const bf16x8*>(
              reinterpret_cast<char*>(Vt) + d * 128 + cb);
          oacc[dt] = __builtin_amdgcn_mfma_f32_16x16x32_bf16(ap[js], bv, oacc[dt], 0, 0, 0);
        }
      }
      __builtin_amdgcn_s_setprio(0);
    }
  }
  float inv[4];
#pragma unroll
  for (int r = 0; r < 4; ++r) inv[r] = 1.f / lsum[r];
  size_t obase = (size_t)(b * S_ + qw0) * D_ + h * 64;
#pragma unroll
  for (int dt = 0; dt < 4; ++dt)
#pragma unroll
    for (int r = 0; r < 4; ++r)
      out[obase + (size_t)(l4 * 4 + r) * D_ + dt * 16 + lc] = f2bf(oacc[dt][r] * inv[r]);
}

// ---------------- shared fragment helpers for BK=32 tiles (row stride 64 B)
DEV bf16x8 read_frag(const u16* tile, int r16, int lane) {
  int r = r16 + (lane & 15);
  int cb = ((lane >> 4) << 4) ^ (((r >> 1) & 3) << 4);
  return *reinterpret_cast<const bf16x8*>(reinterpret_cast<const char*>(tile) + r * 64 + cb);
}

DEV void stage_tile(const u16* __restrict__ src, int ld, int rowBase, int kBase,
                    u16* tile, int tid) {
#pragma unroll
  for (int c = 0; c < 2; ++c) {
    int row = c * 64 + (tid >> 2);
    int cbs = ((tid & 3) << 4) ^ (((row >> 1) & 3) << 4);
    const char* g = reinterpret_cast<const char*>(src + (size_t)(rowBase + row) * ld + kBase) + cbs;
    char* l = reinterpret_cast<char*>(tile) + c * 4096 + (tid >> 6) * 1024;
    __builtin_amdgcn_global_load_lds((gptr_t)g, (lptr_t)l, 16, 0, 0);
  }
}

DEV void stage64(const u16* __restrict__ src, int ld, int rowBase, int kBase,
                 u16* tile, int tid) {
  int row = tid >> 2;
  int cbs = ((tid & 3) << 4) ^ (((row >> 1) & 3) << 4);
  const char* g = reinterpret_cast<const char*>(src + (size_t)(rowBase + row) * ld + kBase) + cbs;
  char* l = reinterpret_cast<char*>(tile) + (tid >> 6) * 1024;
  __builtin_amdgcn_global_load_lds((gptr_t)g, (lptr_t)l, 16, 0, 0);
}

#define BAR()   asm volatile("s_barrier" ::: "memory")

// ---------------- 64x128 gemm, 4-deep pipelined, counted vmcnt (3 loads/tile)
__global__ __launch_bounds__(256, 2) void gemm64(const u16* __restrict__ A,
                                                 const u16* __restrict__ Bt,
                                                 int M, int N, int K,
                                                 float* __restrict__ Cv,
                                                 const float* __restrict__ gate,
                                                 const float* __restrict__ resid) {
  __shared__ __align__(16) u16 ldsA[4][2048];
  __shared__ __align__(16) u16 ldsB[4][4096];
  int tid = threadIdx.x;
  int lane = tid & 63;
  int w = tid >> 6;
  int wr = w >> 1, wc = w & 1;
  int m0 = blockIdx.y * 64;
  int n0 = blockIdx.x * 128;
  f32x4 zero = {0.f, 0.f, 0.f, 0.f};
  f32x4 acc[2][4];
#pragma unroll
  for (int i = 0; i < 2; ++i)
#pragma unroll
    for (int j = 0; j < 4; ++j) acc[i][j] = zero;
  int nt = K >> 5;
#pragma unroll
  for (int p = 0; p < 3; ++p) {
    stage64(A, K, m0, p << 5, &ldsA[p][0], tid);
    stage_tile(Bt, K, n0, p << 5, &ldsB[p][0], tid);
  }
  asm volatile("s_waitcnt vmcnt(6)" ::: "memory");
  BAR();
  for (int t = 0; t < nt; ++t) {
    bf16x8 af[2], bfr[4];
#pragma unroll
    for (int i = 0; i < 2; ++i) af[i] = read_frag(&ldsA[t & 3][0], wr * 32 + i * 16, lane);
#pragma unroll
    for (int i = 0; i < 4; ++i) bfr[i] = read_frag(&ldsB[t & 3][0], wc * 64 + i * 16, lane);
    if (t + 3 < nt) {
      stage64(A, K, m0, (t + 3) << 5, &ldsA[(t + 3) & 3][0], tid);
      stage_tile(Bt, K, n0, (t + 3) << 5, &ldsB[(t + 3) & 3][0], tid);
    }
    __builtin_amdgcn_s_setprio(1);
#pragma unroll
    for (int i = 0; i < 2; ++i)
#pragma unroll
      for (int j = 0; j < 4; ++j)
        acc[i][j] = __builtin_amdgcn_mfma_f32_16x16x32_bf16(af[i], bfr[j], acc[i][j], 0, 0, 0);
    __builtin_amdgcn_s_setprio(0);
    if (t + 3 < nt)      asm volatile("s_waitcnt vmcnt(6)" ::: "memory");
    else if (t + 2 < nt) asm volatile("s_waitcnt vmcnt(3)" ::: "memory");
    else                 asm volatile("s_waitcnt vmcnt(0)" ::: "memory");
    BAR();
  }
  int rowB = m0 + wr * 32 + ((lane >> 4) << 2);
  int colB = n0 + wc * 64 + (lane & 15);
#pragma unroll
  for (int i = 0; i < 2; ++i) {
#pragma unroll
    for (int j = 0; j < 4; ++j) {
      int col = colB + j * 16;
#pragma unroll
      for (int jr = 0; jr < 4; ++jr) {
        int row = rowB + i * 16 + jr;
        float v = acc[i][j][jr];
        size_t idx = (size_t)row * N + col;
        int bb = row >> 11;
        Cv[idx] = resid[idx] + gate[bb * 3072 + col] * v;
      }
    }
  }
}

// ================== 256x256 GEMM, BK=64, A 3-ring, 1 barrier/tile (R16-proven) ==================
DEV bf16x8 readFrag128(const u16* halfBase, int rowInHalf, int ks, int l4) {
  int cb = ((ks << 6) + (l4 << 4)) ^ ((rowInHalf & 7) << 4);
  return *reinterpret_cast<const bf16x8*>(
      reinterpret_cast<const char*>(halfBase) + rowInHalf * 128 + cb);
}

DEV void stageHalf(const u16* __restrict__ src, int ld, int rowBase, int kBase,
                   u16* halfBase, int tid) {
#pragma unroll
  for (int c = 0; c < 2; ++c) {
    int row = c * 64 + (tid >> 3);
    int cbs = (((tid & 7) ^ ((tid >> 3) & 7)) << 4);
    const char* g = reinterpret_cast<const char*>(src + (size_t)(rowBase + row) * ld + kBase) + cbs;
    char* l = reinterpret_cast<char*>(halfBase) + c * 8192 + (tid >> 6) * 1024;
    __builtin_amdgcn_global_load_lds((gptr_t)g, (lptr_t)l, 16, 0, 0);
  }
}

// EPI 2: bf16 store | EPI 3: fused swiglu on 16-col-interleaved B layout
template <int EPI>
__global__ __launch_bounds__(512, 1) void gemm8p(const u16* __restrict__ A,
                                                 const u16* __restrict__ Bt,
                                                 int M, int N, int K,
                                                 void* __restrict__ Cv) {
  extern __shared__ __align__(16) u16 smem[];
  u16* Abase = smem;            // 3 bufs x 32 KiB = 96 KiB
  u16* Bbase = smem + 49152;    // 2 bufs x 32 KiB = 64 KiB
  int tid = threadIdx.x, lane = tid & 63, w = tid >> 6;
  int wm = w >> 2, wn = w & 3;
  int l4 = lane >> 4, lc = lane & 15;
  int wg = ((int)blockIdx.x & 7) * ((int)gridDim.x >> 3) + ((int)blockIdx.x >> 3);
  int nby = M >> 8;
  int bx = wg / nby, by = wg % nby;
  int m0 = by << 8, n0 = bx << 8;
  int NT = K >> 6;
  f32x4 zero = {0.f, 0.f, 0.f, 0.f};
  f32x4 acc[8][4];
#pragma unroll
  for (int i = 0; i < 8; ++i)
#pragma unroll
    for (int j = 0; j < 4; ++j) acc[i][j] = zero;
  stageHalf(A, K, m0, 0, Abase, tid);
  stageHalf(A, K, m0 + 128, 0, Abase + 8192, tid);
  stageHalf(Bt, K, n0, 0, Bbase, tid);
  stageHalf(Bt, K, n0 + 128, 0, Bbase + 8192, tid);
  stageHalf(A, K, m0, 64, Abase + 16384, tid);
  stageHalf(A, K, m0 + 128, 64, Abase + 16384 + 8192, tid);
  asm volatile("s_waitcnt vmcnt(4)" ::: "memory");
  BAR();
  int rBq = (wn & 1) * 64;
  int ab = 0;   // t % 3
  for (int t = 0; t < NT; ++t) {
    const u16* Ah = Abase + ab * 16384 + wm * 8192;
    const u16* Bh = Bbase + (t & 1) * 16384 + (wn >> 1) * 8192;
    u16* Bdst = Bbase + ((t + 1) & 1) * 16384;
    int ad = ab + 2; if (ad >= 3) ad -= 3;
    u16* Adst = Abase + ad * 16384;
    int kN1 = (t + 1) << 6, kN2 = (t + 2) << 6;
    bf16x8 aLo[4][2], aHi[4][2], bFr[2][2];
    // ---- phase 1: read A-lo + B-lo; stage B0(t+1); MFMA Q(lo,lo)
#pragma unroll
    for (int mi = 0; mi < 4; ++mi)
#pragma unroll
      for (int ks = 0; ks < 2; ++ks)
        aLo[mi][ks] = readFrag128(Ah, mi * 16 + lc, ks, l4);
#pragma unroll
    for (int j = 0; j < 2; ++j)
#pragma unroll
      for (int ks = 0; ks < 2; ++ks)
        bFr[j][ks] = readFrag128(Bh, rBq + j * 16 + lc, ks, l4);
    if (t + 1 < NT) stageHalf(Bt, K, n0, kN1, Bdst, tid);
    __builtin_amdgcn_s_setprio(1);
#pragma unroll
    for (int mi = 0; mi < 4; ++mi)
#pragma unroll
      for (int j = 0; j < 2; ++j)
#pragma unroll
        for (int ks = 0; ks < 2; ++ks)
          acc[mi][j] = __builtin_amdgcn_mfma_f32_16x16x32_bf16(aLo[mi][ks], bFr[j][ks], acc[mi][j], 0, 0, 0);
    __builtin_amdgcn_s_setprio(0);
    // ---- phase 2: read A-hi; stage B1(t+1); MFMA Q(hi,lo)
#pragma unroll
    for (int mi = 0; mi < 4; ++mi)
#pragma unroll
      for (int ks = 0; ks < 2; ++ks)
        aHi[mi][ks] = readFrag128(Ah, 64 + mi * 16 + lc, ks, l4);
    if (t + 1 < NT) stageHalf(Bt, K, n0 + 128, kN1, Bdst + 8192, tid);
    __builtin_amdgcn_s_setprio(1);
#pragma unroll
    for (int mi = 0; mi < 4; ++mi)
#pragma unroll
      for (int j = 0; j < 2; ++j)
#pragma unroll
        for (int ks = 0; ks < 2; ++ks)
          acc[4 + mi][j] = __builtin_amdgcn_mfma_f32_16x16x32_bf16(aHi[mi][ks], bFr[j][ks], acc[4 + mi][j], 0, 0, 0);
    __builtin_amdgcn_s_setprio(0);
    // ---- phase 3: read B-hi; stage A(t+2) into ring slot
#pragma unroll
    for (int j = 0; j < 2; ++j)
#pragma unroll
      for (int ks = 0; ks < 2; ++ks)
        bFr[j][ks] = readFrag128(Bh, rBq + (2 + j) * 16 + lc, ks, l4);
    if (t + 2 < NT) {
      stageHalf(A, K, m0, kN2, Adst, tid);
      stageHalf(A, K, m0 + 128, kN2, Adst + 8192, tid);
    }
    __builtin_amdgcn_s_setprio(1);
#pragma unroll
    for (int mi = 0; mi < 4; ++mi)
#pragma unroll
      for (int j = 0; j < 2; ++j)
#pragma unroll
        for (int ks = 0; ks < 2; ++ks)
          acc[mi][2 + j] = __builtin_amdgcn_mfma_f32_16x16x32_bf16(aLo[mi][ks], bFr[j][ks], acc[mi][2 + j], 0, 0, 0);
    __builtin_amdgcn_s_setprio(0);
    // ---- phase 4: MFMA Q(hi,hi); counted vmcnt; single end-of-tile barrier
    __builtin_amdgcn_s_setprio(1);
#pragma unroll
    for (int mi = 0; mi < 4; ++mi)
#pragma unroll
      for (int j = 0; j < 2; ++j)
#pragma unroll
        for (int ks = 0; ks < 2; ++ks)
          acc[4 + mi][2 + j] = __builtin_amdgcn_mfma_f32_16x16x32_bf16(aHi[mi][ks], bFr[j][ks], acc[4 + mi][2 + j], 0, 0, 0);
    __builtin_amdgcn_s_setprio(0);
    if (t + 2 < NT) asm volatile("s_waitcnt vmcnt(4)" ::: "memory");
    else            asm volatile("s_waitcnt vmcnt(0)" ::: "memory");
    BAR();
    ab = (ab == 2) ? 0 : ab + 1;
  }
  // epilogue
  if constexpr (EPI == 3) {
    u16* swig = reinterpret_cast<u16*>(Cv);
    int scolB = (n0 >> 1) + wn * 32 + lc;
#pragma unroll
    for (int mi = 0; mi < 8; ++mi) {
      int row0 = m0 + wm * 128 + (mi >> 2) * 64 + (mi & 3) * 16 + l4 * 4;
#pragma unroll
      for (int jp = 0; jp < 2; ++jp)
#pragma unroll
        for (int jr = 0; jr < 4; ++jr) {
          float a = acc[mi][jp * 2][jr];
          float b3 = acc[mi][jp * 2 + 1][jr];
          float sv = a / (1.f + __expf(-a)) * b3;
          swig[(size_t)(row0 + jr) * 4096 + scolB + jp * 16] = f2bf(sv);
        }
    }
  } else {
    u16* Cb = reinterpret_cast<u16*>(Cv);
    int colB = n0 + wn * 64 + lc;
#pragma unroll
    for (int mi = 0; mi < 8; ++mi) {
      int row0 = m0 + wm * 128 + (mi >> 2) * 64 + (mi & 3) * 16 + l4 * 4;
#pragma unroll
      for (int j = 0; j < 4; ++j)
#pragma unroll
        for (int jr = 0; jr < 4; ++jr)
          Cb[(size_t)(row0 + jr) * N + colB + j * 16] = f2bf(acc[mi][j][jr]);
    }
  }
}

extern "C" void kernel_launch(void* const* d_in, const int* in_sizes, int n_in,
                              void* d_out, int out_size, void* d_ws, size_t ws_size,
                              hipStream_t stream) {
  const float* x    = (const float*)d_in[0];
  const float* rc   = (const float*)d_in[1];
  const float* rs   = (const float*)d_in[2];
  const float* cond = (const float*)d_in[3];
  const float* wq   = (const float*)d_in[4];
  const float* wk   = (const float*)d_in[5];
  const float* wv   = (const float*)d_in[6];
  const float* wo   = (const float*)d_in[7];
  const float* aaw  = (const float*)d_in[8];
  const float* aab  = (const float*)d_in[9];
  const float* afw  = (const float*)d_in[10];
  const float* afb  = (const float*)d_in[11];
  const float* w1   = (const float*)d_in[12];
  const float* w3   = (const float*)d_in[13];
  const float* w2   = (const float*)d_in[14];
  float* out = (float*)d_out;
  char* ws = (char*)d_ws;

  u16*   wt_qkv = (u16*)  (ws + 0);
  u16*   wt_o   = (u16*)  (ws + 6291456);
  u16*   wt_13  = (u16*)  (ws + 8388608);
  u16*   wt_2   = (u16*)  (ws + 25165824);
  float* modf   = (float*)(ws + 33554432);
  u16*   norm_b = (u16*)  (ws + 33603584);
  u16*   attn_b = (u16*)  (ws + 41992192);
  u16*   qkv_bf = (u16*)  (ws + 50380800);
  float* adpart = (float*)(ws + 50380800);
  float* hbuf   = (float*)(ws + 117489664);
  u16*   swig_b = (u16*)  (ws + 134266880);

  {
    auto f2 = gemm8p<2>; auto f3 = gemm8p<3>;
    hipFuncSetAttribute((const void*)f2, hipFuncAttributeMaxDynamicSharedMemorySize, 163840);
    hipFuncSetAttribute((const void*)f3, hipFuncAttributeMaxDynamicSharedMemorySize, 163840);
  }

  prep_all<<<16768, 256, 0, stream>>>(wq, wk, wv, wo, w1, w3, w2, cond, aaw, afw,
                                      wt_qkv, wt_o, wt_13, wt_2, adpart);
  adaln_reduce<<<dim3(12, 4), 256, 0, stream>>>(adpart, aab, afb, modf);

  ln_mod_kernel<<<4096, 256, 0, stream>>>(x, modf, norm_b);
  gemm8p<2><<<dim3(192), 512, 163840, stream>>>(norm_b, wt_qkv, M_, 3072, 1024, qkv_bf);
  rope_k<<<8192, 256, 0, stream>>>(qkv_bf, rc, rs);
  attn_mfma<<<dim3(32, 16, 2), 256, 0, stream>>>(qkv_bf, rc, rs, attn_b);
  gemm64<<<dim3(8, 64), 256, 0, stream>>>(attn_b, wt_o, M_, 1024, 1024, hbuf, modf + 2048, x);
  ln_mod_kernel<<<4096, 256, 0, stream>>>(hbuf, modf + 6144, norm_b);
  gemm8p<3><<<dim3(512), 512, 163840, stream>>>(norm_b, wt_13, M_, 8192, 1024, swig_b);
  gemm64<<<dim3(8, 64), 256, 0, stream>>>(swig_b, wt_2, M_, 1024, 4096, out, modf + 6144 + 2048, hbuf);
}

// Round 20
// 249.942 us; speedup vs baseline: 1.0506x; 1.0052x over previous
//
#include <hip/hip_runtime.h>

#define DEV __device__ __forceinline__

using bf16x8 = __attribute__((ext_vector_type(8))) short;
using f32x4  = __attribute__((ext_vector_type(4))) float;
using u16 = unsigned short;

constexpr int S_   = 2048;
constexpr int D_   = 1024;
constexpr int M_   = 4096;   // B*S tokens
constexpr int WIN_ = 256;
constexpr float SCALE_ = 0.125f;

typedef const __attribute__((address_space(1))) void* gptr_t;
typedef __attribute__((address_space(3))) void* lptr_t;

DEV u16 f2bf(float f) {
  unsigned u = __builtin_bit_cast(unsigned, f);
  return (u16)((u + 0x7fffu + ((u >> 16) & 1u)) >> 16);
}
DEV float bf2f(u16 b) {
  unsigned u = ((unsigned)b) << 16;
  return __builtin_bit_cast(float, u);
}

// ---------------- merged preprocessing: all weight transposes + adaln partials
__global__ __launch_bounds__(256) void prep_all(const float* __restrict__ wq,
                                                const float* __restrict__ wk,
                                                const float* __restrict__ wv,
                                                const float* __restrict__ wo,
                                                const float* __restrict__ w1,
                                                const float* __restrict__ w3,
                                                const float* __restrict__ w2,
                                                const float* __restrict__ cond,
                                                const float* __restrict__ aaw,
                                                const float* __restrict__ afw,
                                                u16* wt_qkv, u16* wt_o,
                                                u16* wt_13, u16* wt_2,
                                                float* part) {
  __shared__ float tile[32][33];
  __shared__ float sc[128];
  int idx = blockIdx.x;
  int tx = threadIdx.x & 31, ty = threadIdx.x >> 5;
  if (idx < 4096) {
    int z = idx >> 10, t = idx & 1023;
    const float* src; u16* dst;
    switch (z) {
      case 0: src = wq; dst = wt_qkv; break;
      case 1: src = wk; dst = wt_qkv + 1048576; break;
      case 2: src = wv; dst = wt_qkv + 2097152; break;
      default: src = wo; dst = wt_o;
    }
    int n0 = (t & 31) * 32, k0 = (t >> 5) * 32;
#pragma unroll
    for (int p = 0; p < 4; ++p)
      tile[ty + p * 8][tx] = src[(size_t)(k0 + ty + p * 8) * 1024 + n0 + tx];
    __syncthreads();
#pragma unroll
    for (int p = 0; p < 4; ++p)
      dst[(size_t)(n0 + ty + p * 8) * 1024 + k0 + tx] = f2bf(tile[tx][ty + p * 8]);
  } else if (idx < 12288) {
    int i2 = idx - 4096;
    int z = i2 >> 12, t = i2 & 4095;
    const float* src = z ? w3 : w1;
    int add = z ? 16 : 0;
    int n0 = (t & 127) * 32, k0 = (t >> 7) * 32;
#pragma unroll
    for (int p = 0; p < 4; ++p)
      tile[ty + p * 8][tx] = src[(size_t)(k0 + ty + p * 8) * 4096 + n0 + tx];
    __syncthreads();
#pragma unroll
    for (int p = 0; p < 4; ++p) {
      int n = n0 + ty + p * 8;
      int r = ((n >> 4) << 5) + add + (n & 15);
      wt_13[(size_t)r * 1024 + k0 + tx] = f2bf(tile[tx][ty + p * 8]);
    }
  } else if (idx < 16384) {
    int i3 = idx - 12288;
    int n0 = (i3 & 31) * 32, k0 = (i3 >> 5) * 32;
#pragma unroll
    for (int p = 0; p < 4; ++p)
      tile[ty + p * 8][tx] = w2[(size_t)(k0 + ty + p * 8) * 1024 + n0 + tx];
    __syncthreads();
#pragma unroll
    for (int p = 0; p < 4; ++p)
      wt_2[(size_t)(n0 + ty + p * 8) * 4096 + k0 + tx] = f2bf(tile[tx][ty + p * 8]);
  } else {
    int p = idx - 16384;
    int xb = p % 12;
    int rest = p / 12;
    int ks = rest & 7, sb = rest >> 3;
    int b = sb & 1;
    const float* W = (sb & 2) ? afw : aaw;
    if (threadIdx.x < 128) {
      float c = cond[b * 1024 + ks * 128 + threadIdx.x];
      sc[threadIdx.x] = c / (1.f + __expf(-c));
    }
    __syncthreads();
    int n = xb * 256 + threadIdx.x;
    float acc = 0.f;
    const float* Wp = W + (size_t)(ks * 128) * 3072 + n;
#pragma unroll 4
    for (int c = 0; c < 128; ++c) acc += sc[c] * Wp[(size_t)c * 3072];
    part[(size_t)(sb * 8 + ks) * 3072 + n] = acc;
  }
}

__global__ __launch_bounds__(256) void adaln_reduce(const float* __restrict__ part,
                                                    const float* __restrict__ ba,
                                                    const float* __restrict__ bfb,
                                                    float* __restrict__ modout) {
  int n = blockIdx.x * 256 + threadIdx.x;
  int sb = blockIdx.y;
  float acc = ((sb & 2) ? bfb : ba)[n];
#pragma unroll
  for (int k = 0; k < 8; ++k) acc += part[(size_t)(sb * 8 + k) * 3072 + n];
  modout[sb * 3072 + n] = acc;
}

// ---------------- LayerNorm + (1+scale)*x + shift -> bf16 ; BF selects input dtype
template <int BF>
__global__ __launch_bounds__(256) void ln_mod_kernel(const void* __restrict__ xv,
                                                     const float* __restrict__ modset,
                                                     u16* __restrict__ out) {
  int m = blockIdx.x;
  int b = m >> 11;
  int tid = threadIdx.x;
  float4 v;
  if constexpr (BF) {
    const u16* row = reinterpret_cast<const u16*>(xv) + (size_t)m * D_;
    ushort4 u4 = *reinterpret_cast<const ushort4*>(row + tid * 4);
    v.x = bf2f(u4.x); v.y = bf2f(u4.y); v.z = bf2f(u4.z); v.w = bf2f(u4.w);
  } else {
    v = reinterpret_cast<const float4*>(
        reinterpret_cast<const float*>(xv) + (size_t)m * D_)[tid];
  }
  float s = v.x + v.y + v.z + v.w;
  float ss = v.x * v.x + v.y * v.y + v.z * v.z + v.w * v.w;
#pragma unroll
  for (int o = 1; o < 64; o <<= 1) { s += __shfl_xor(s, o); ss += __shfl_xor(ss, o); }
  __shared__ float rs[4], rq[4];
  if ((tid & 63) == 0) { rs[tid >> 6] = s; rq[tid >> 6] = ss; }
  __syncthreads();
  s = rs[0] + rs[1] + rs[2] + rs[3];
  ss = rq[0] + rq[1] + rq[2] + rq[3];
  float mu = s * (1.f / D_);
  float rinv = rsqrtf(ss * (1.f / D_) - mu * mu + 1e-5f);
  int n = tid * 4;
  const float* mb = modset + b * 3072;
  float4 sh = *reinterpret_cast<const float4*>(mb + n);
  float4 sc = *reinterpret_cast<const float4*>(mb + 1024 + n);
  ushort4 o4;
  o4.x = f2bf((v.x - mu) * rinv * (1.f + sc.x) + sh.x);
  o4.y = f2bf((v.y - mu) * rinv * (1.f + sc.y) + sh.y);
  o4.z = f2bf((v.z - mu) * rinv * (1.f + sc.z) + sh.z);
  o4.w = f2bf((v.w - mu) * rinv * (1.f + sc.w) + sh.w);
  *reinterpret_cast<ushort4*>(out + (size_t)m * D_ + n) = o4;
}

// ---------------- rotate 4 (even,odd) bf16 pairs
DEV bf16x8 rope8(bf16x8 v, const float* __restrict__ cs, const float* __restrict__ sn,
                 int s, int base) {
  bf16x8 r;
#pragma unroll
  for (int t = 0; t < 4; ++t) {
    float c = cs[s * 32 + base + t], si = sn[s * 32 + base + t];
    float x = bf2f((u16)v[2 * t]), y = bf2f((u16)v[2 * t + 1]);
    r[2 * t] = (short)f2bf(x * c - y * si);
    r[2 * t + 1] = (short)f2bf(x * si + y * c);
  }
  return r;
}

// ---------------- RoPE on K plane only (in-place, once per token)
__global__ __launch_bounds__(256) void rope_k(u16* __restrict__ qkv,
                                              const float* __restrict__ cs,
                                              const float* __restrict__ sn) {
  int idx = blockIdx.x * 256 + threadIdx.x;
  int i = idx & 31;
  int hh = (idx >> 5) & 15;
  int mm = idx >> 9;
  int s = mm & (S_ - 1);
  float c = cs[s * 32 + i], si = sn[s * 32 + i];
  unsigned* kp = reinterpret_cast<unsigned*>(qkv + (size_t)mm * 3072 + 1024 + hh * 64 + 2 * i);
  unsigned kv = *kp;
  float kx = bf2f((u16)(kv & 0xffff)), ky = bf2f((u16)(kv >> 16));
  *kp = (unsigned)f2bf(kx * c - ky * si) | ((unsigned)f2bf(kx * si + ky * c) << 16);
}

// ---------------- MFMA sliding-window flash attention, KVBLK=64 (K pre-roped; Q roped at load)
__global__ __launch_bounds__(256) void attn_mfma(const u16* __restrict__ qkv,
                                                 const float* __restrict__ cs,
                                                 const float* __restrict__ sn,
                                                 u16* __restrict__ out) {
  int qb = (int)blockIdx.x;
  int qbe = (qb & 7) * 4 + (qb >> 3);
  int q0 = qbe * 64;
  int h = blockIdx.y, b = blockIdx.z;
  __shared__ __align__(16) u16 Ks[4096];
  __shared__ __align__(16) u16 Vt[4096];
  __shared__ __align__(16) u16 Ps[4][16][72];
  int tid = threadIdx.x, lane = tid & 63, w = tid >> 6;
  int l4 = lane >> 4, lc = lane & 15;
  int sq = q0 + w * 16 + lc;
  const u16* qrow = qkv + (size_t)(b * S_ + sq) * 3072 + h * 64;
  bf16x8 aq0 = rope8(*reinterpret_cast<const bf16x8*>(qrow + l4 * 8), cs, sn, sq, l4 * 4);
  bf16x8 aq1 = rope8(*reinterpret_cast<const bf16x8*>(qrow + 32 + l4 * 8), cs, sn, sq, 16 + l4 * 4);
  int qw0 = q0 + w * 16;
  float mrow[4], lsum[4];
  f32x4 oacc[4];
#pragma unroll
  for (int r = 0; r < 4; ++r) {
    mrow[r] = -__builtin_inff(); lsum[r] = 0.f;
    oacc[r] = f32x4{0.f, 0.f, 0.f, 0.f};
  }
  int kj = lane >> 3;
  int kcb = (lane & 7) * 16;
  int vj = tid & 63;
  int vd0h = (tid >> 6) * 8;
  int jstart = q0 - WIN_; if (jstart < 0) jstart = 0;
  for (int jb = jstart; jb < q0 + 64; jb += 64) {
    __syncthreads();
#pragma unroll
    for (int c = 0; c < 2; ++c) {
      int j = c * 32 + w * 8 + kj;
      const char* src = reinterpret_cast<const char*>(
          qkv + (size_t)(b * S_ + jb + j) * 3072 + 1024 + h * 64) + (kcb ^ ((j & 7) << 4));
      __builtin_amdgcn_global_load_lds((gptr_t)src,
          (lptr_t)(reinterpret_cast<char*>(Ks) + c * 4096 + w * 1024), 16, 0, 0);
    }
#pragma unroll
    for (int half = 0; half < 2; ++half) {
      int dbase = vd0h + half * 32;
      bf16x8 v = *reinterpret_cast<const bf16x8*>(
          qkv + (size_t)(b * S_ + jb + vj) * 3072 + 2048 + h * 64 + dbase);
#pragma unroll
      for (int k2 = 0; k2 < 8; ++k2) {
        int d = dbase + k2;
        int cb = (2 * vj) ^ ((d & 7) << 4);
        *reinterpret_cast<u16*>(reinterpret_cast<char*>(Vt) + d * 128 + cb) = (u16)v[k2];
      }
    }
    __syncthreads();
    if (jb + 63 >= qw0 - WIN_ && jb <= qw0 + 15) {
      f32x4 sacc[4] = {f32x4{0,0,0,0}, f32x4{0,0,0,0}, f32x4{0,0,0,0}, f32x4{0,0,0,0}};
      __builtin_amdgcn_s_setprio(1);
#pragma unroll
      for (int jt = 0; jt < 4; ++jt) {
        int j = jt * 16 + lc;
#pragma unroll
        for (int kh = 0; kh < 2; ++kh) {
          int cbb = (kh * 64 + l4 * 16) ^ ((j & 7) << 4);
          bf16x8 bk = *reinterpret_cast<const bf16x8*>(
              reinterpret_cast<char*>(Ks) + j * 128 + cbb);
          sacc[jt] = __builtin_amdgcn_mfma_f32_16x16x32_bf16(kh == 0 ? aq0 : aq1, bk, sacc[jt], 0, 0, 0);
        }
      }
      __builtin_amdgcn_s_setprio(0);
      float pv[4][4], rr[4];
#pragma unroll
      for (int r = 0; r < 4; ++r) {
        int qa = qw0 + l4 * 4 + r;
        float se[4];
        float cm = -__builtin_inff();
#pragma unroll
        for (int jt = 0; jt < 4; ++jt) {
          int ja = jb + jt * 16 + lc;
          bool val = (ja <= qa) && (qa - ja <= WIN_);
          se[jt] = val ? sacc[jt][r] * SCALE_ : -__builtin_inff();
          cm = fmaxf(cm, se[jt]);
        }
        cm = fmaxf(cm, __shfl_xor(cm, 1));
        cm = fmaxf(cm, __shfl_xor(cm, 2));
        cm = fmaxf(cm, __shfl_xor(cm, 4));
        cm = fmaxf(cm, __shfl_xor(cm, 8));
        float mnew = fmaxf(mrow[r], cm);
        float esum = 0.f;
#pragma unroll
        for (int jt = 0; jt < 4; ++jt) {
          float e = __expf(se[jt] - mnew);
          e = (se[jt] == -__builtin_inff()) ? 0.f : e;
          pv[jt][r] = e;
          esum += e;
        }
        esum += __shfl_xor(esum, 1);
        esum += __shfl_xor(esum, 2);
        esum += __shfl_xor(esum, 4);
        esum += __shfl_xor(esum, 8);
        float rf = __expf(mrow[r] - mnew);
        rf = (mnew == -__builtin_inff()) ? 0.f : rf;
        rr[r] = rf;
        lsum[r] = lsum[r] * rf + esum;
        mrow[r] = mnew;
      }
#pragma unroll
      for (int jt = 0; jt < 4; ++jt)
#pragma unroll
        for (int r = 0; r < 4; ++r)
          Ps[w][l4 * 4 + r][jt * 16 + lc] = f2bf(pv[jt][r]);
      asm volatile("s_waitcnt lgkmcnt(0)" ::: "memory");
      __builtin_amdgcn_sched_barrier(0);
      bf16x8 ap[2];
#pragma unroll
      for (int js = 0; js < 2; ++js)
        ap[js] = *reinterpret_cast<const bf16x8*>(&Ps[w][lc][js * 32 + l4 * 8]);
      __builtin_amdgcn_s_setprio(1);
#pragma unroll
      for (int dt = 0; dt < 4; ++dt) {
        int d = dt * 16 + lc;
#pragma unroll
        for (int r = 0; r < 4; ++r) oacc[dt][r] *= rr[r];
#pragma unroll
        for (int js = 0; js < 2; ++js) {
          int cb = (js * 64 + l4 * 16) ^ ((d & 7) << 4);
          bf16x8 bv = *reinterpret_cast<const bf16x8*>(
              reinterpret_cast<char*>(Vt) + d * 128 + cb);
          oacc[dt] = __builtin_amdgcn_mfma_f32_16x16x32_bf16(ap[js], bv, oacc[dt], 0, 0, 0);
        }
      }
      __builtin_amdgcn_s_setprio(0);
    }
  }
  float inv[4];
#pragma unroll
  for (int r = 0; r < 4; ++r) inv[r] = 1.f / lsum[r];
  size_t obase = (size_t)(b * S_ + qw0) * D_ + h * 64;
#pragma unroll
  for (int dt = 0; dt < 4; ++dt)
#pragma unroll
    for (int r = 0; r < 4; ++r)
      out[obase + (size_t)(l4 * 4 + r) * D_ + dt * 16 + lc] = f2bf(oacc[dt][r] * inv[r]);
}

// ---------------- shared fragment helpers for BK=32 tiles (row stride 64 B)
DEV bf16x8 read_frag(const u16* tile, int r16, int lane) {
  int r = r16 + (lane & 15);
  int cb = ((lane >> 4) << 4) ^ (((r >> 1) & 3) << 4);
  return *reinterpret_cast<const bf16x8*>(reinterpret_cast<const char*>(tile) + r * 64 + cb);
}

DEV void stage_tile(const u16* __restrict__ src, int ld, int rowBase, int kBase,
                    u16* tile, int tid) {
#pragma unroll
  for (int c = 0; c < 2; ++c) {
    int row = c * 64 + (tid >> 2);
    int cbs = ((tid & 3) << 4) ^ (((row >> 1) & 3) << 4);
    const char* g = reinterpret_cast<const char*>(src + (size_t)(rowBase + row) * ld + kBase) + cbs;
    char* l = reinterpret_cast<char*>(tile) + c * 4096 + (tid >> 6) * 1024;
    __builtin_amdgcn_global_load_lds((gptr_t)g, (lptr_t)l, 16, 0, 0);
  }
}

DEV void stage64(const u16* __restrict__ src, int ld, int rowBase, int kBase,
                 u16* tile, int tid) {
  int row = tid >> 2;
  int cbs = ((tid & 3) << 4) ^ (((row >> 1) & 3) << 4);
  const char* g = reinterpret_cast<const char*>(src + (size_t)(rowBase + row) * ld + kBase) + cbs;
  char* l = reinterpret_cast<char*>(tile) + (tid >> 6) * 1024;
  __builtin_amdgcn_global_load_lds((gptr_t)g, (lptr_t)l, 16, 0, 0);
}

#define BAR()   asm volatile("s_barrier" ::: "memory")

// ---------------- 64x128 gemm, 4-deep pipelined, counted vmcnt.
// RBF: residual dtype (0=f32,1=bf16) | OBF: output dtype (0=f32,1=bf16)
template <int RBF, int OBF>
__global__ __launch_bounds__(256, 2) void gemm64(const u16* __restrict__ A,
                                                 const u16* __restrict__ Bt,
                                                 int M, int N, int K,
                                                 void* __restrict__ Cv,
                                                 const float* __restrict__ gate,
                                                 const void* __restrict__ resid) {
  __shared__ __align__(16) u16 ldsA[4][2048];
  __shared__ __align__(16) u16 ldsB[4][4096];
  int tid = threadIdx.x;
  int lane = tid & 63;
  int w = tid >> 6;
  int wr = w >> 1, wc = w & 1;
  int m0 = blockIdx.y * 64;
  int n0 = blockIdx.x * 128;
  f32x4 zero = {0.f, 0.f, 0.f, 0.f};
  f32x4 acc[2][4];
#pragma unroll
  for (int i = 0; i < 2; ++i)
#pragma unroll
    for (int j = 0; j < 4; ++j) acc[i][j] = zero;
  int nt = K >> 5;
#pragma unroll
  for (int p = 0; p < 3; ++p) {
    stage64(A, K, m0, p << 5, &ldsA[p][0], tid);
    stage_tile(Bt, K, n0, p << 5, &ldsB[p][0], tid);
  }
  asm volatile("s_waitcnt vmcnt(6)" ::: "memory");
  BAR();
  for (int t = 0; t < nt; ++t) {
    bf16x8 af[2], bfr[4];
#pragma unroll
    for (int i = 0; i < 2; ++i) af[i] = read_frag(&ldsA[t & 3][0], wr * 32 + i * 16, lane);
#pragma unroll
    for (int i = 0; i < 4; ++i) bfr[i] = read_frag(&ldsB[t & 3][0], wc * 64 + i * 16, lane);
    if (t + 3 < nt) {
      stage64(A, K, m0, (t + 3) << 5, &ldsA[(t + 3) & 3][0], tid);
      stage_tile(Bt, K, n0, (t + 3) << 5, &ldsB[(t + 3) & 3][0], tid);
    }
    __builtin_amdgcn_s_setprio(1);
#pragma unroll
    for (int i = 0; i < 2; ++i)
#pragma unroll
      for (int j = 0; j < 4; ++j)
        acc[i][j] = __builtin_amdgcn_mfma_f32_16x16x32_bf16(af[i], bfr[j], acc[i][j], 0, 0, 0);
    __builtin_amdgcn_s_setprio(0);
    if (t + 3 < nt)      asm volatile("s_waitcnt vmcnt(6)" ::: "memory");
    else if (t + 2 < nt) asm volatile("s_waitcnt vmcnt(3)" ::: "memory");
    else                 asm volatile("s_waitcnt vmcnt(0)" ::: "memory");
    BAR();
  }
  int rowB = m0 + wr * 32 + ((lane >> 4) << 2);
  int colB = n0 + wc * 64 + (lane & 15);
#pragma unroll
  for (int i = 0; i < 2; ++i) {
#pragma unroll
    for (int j = 0; j < 4; ++j) {
      int col = colB + j * 16;
#pragma unroll
      for (int jr = 0; jr < 4; ++jr) {
        int row = rowB + i * 16 + jr;
        float v = acc[i][j][jr];
        size_t idx = (size_t)row * N + col;
        int bb = row >> 11;
        float rv;
        if constexpr (RBF) rv = bf2f(reinterpret_cast<const u16*>(resid)[idx]);
        else               rv = reinterpret_cast<const float*>(resid)[idx];
        float v2 = rv + gate[bb * 3072 + col] * v;
        if constexpr (OBF) reinterpret_cast<u16*>(Cv)[idx] = f2bf(v2);
        else               reinterpret_cast<float*>(Cv)[idx] = v2;
      }
    }
  }
}

// ================== 256x256 GEMM, BK=64, A 3-ring, 1 barrier/tile (R16-proven) ==================
DEV bf16x8 readFrag128(const u16* halfBase, int rowInHalf, int ks, int l4) {
  int cb = ((ks << 6) + (l4 << 4)) ^ ((rowInHalf & 7) << 4);
  return *reinterpret_cast<const bf16x8*>(
      reinterpret_cast<const char*>(halfBase) + rowInHalf * 128 + cb);
}

DEV void stageHalf(const u16* __restrict__ src, int ld, int rowBase, int kBase,
                   u16* halfBase, int tid) {
#pragma unroll
  for (int c = 0; c < 2; ++c) {
    int row = c * 64 + (tid >> 3);
    int cbs = (((tid & 7) ^ ((tid >> 3) & 7)) << 4);
    const char* g = reinterpret_cast<const char*>(src + (size_t)(rowBase + row) * ld + kBase) + cbs;
    char* l = reinterpret_cast<char*>(halfBase) + c * 8192 + (tid >> 6) * 1024;
    __builtin_amdgcn_global_load_lds((gptr_t)g, (lptr_t)l, 16, 0, 0);
  }
}

// EPI 2: bf16 store | EPI 3: fused swiglu on 16-col-interleaved B layout
template <int EPI>
__global__ __launch_bounds__(512, 1) void gemm8p(const u16* __restrict__ A,
                                                 const u16* __restrict__ Bt,
                                                 int M, int N, int K,
                                                 void* __restrict__ Cv) {
  extern __shared__ __align__(16) u16 smem[];
  u16* Abase = smem;            // 3 bufs x 32 KiB = 96 KiB
  u16* Bbase = smem + 49152;    // 2 bufs x 32 KiB = 64 KiB
  int tid = threadIdx.x, lane = tid & 63, w = tid >> 6;
  int wm = w >> 2, wn = w & 3;
  int l4 = lane >> 4, lc = lane & 15;
  int wg = ((int)blockIdx.x & 7) * ((int)gridDim.x >> 3) + ((int)blockIdx.x >> 3);
  int nby = M >> 8;
  int bx = wg / nby, by = wg % nby;
  int m0 = by << 8, n0 = bx << 8;
  int NT = K >> 6;
  f32x4 zero = {0.f, 0.f, 0.f, 0.f};
  f32x4 acc[8][4];
#pragma unroll
  for (int i = 0; i < 8; ++i)
#pragma unroll
    for (int j = 0; j < 4; ++j) acc[i][j] = zero;
  stageHalf(A, K, m0, 0, Abase, tid);
  stageHalf(A, K, m0 + 128, 0, Abase + 8192, tid);
  stageHalf(Bt, K, n0, 0, Bbase, tid);
  stageHalf(Bt, K, n0 + 128, 0, Bbase + 8192, tid);
  stageHalf(A, K, m0, 64, Abase + 16384, tid);
  stageHalf(A, K, m0 + 128, 64, Abase + 16384 + 8192, tid);
  asm volatile("s_waitcnt vmcnt(4)" ::: "memory");
  BAR();
  int rBq = (wn & 1) * 64;
  int ab = 0;   // t % 3
  for (int t = 0; t < NT; ++t) {
    const u16* Ah = Abase + ab * 16384 + wm * 8192;
    const u16* Bh = Bbase + (t & 1) * 16384 + (wn >> 1) * 8192;
    u16* Bdst = Bbase + ((t + 1) & 1) * 16384;
    int ad = ab + 2; if (ad >= 3) ad -= 3;
    u16* Adst = Abase + ad * 16384;
    int kN1 = (t + 1) << 6, kN2 = (t + 2) << 6;
    bf16x8 aLo[4][2], aHi[4][2], bFr[2][2];
    // ---- phase 1: read A-lo + B-lo; stage B0(t+1); MFMA Q(lo,lo)
#pragma unroll
    for (int mi = 0; mi < 4; ++mi)
#pragma unroll
      for (int ks = 0; ks < 2; ++ks)
        aLo[mi][ks] = readFrag128(Ah, mi * 16 + lc, ks, l4);
#pragma unroll
    for (int j = 0; j < 2; ++j)
#pragma unroll
      for (int ks = 0; ks < 2; ++ks)
        bFr[j][ks] = readFrag128(Bh, rBq + j * 16 + lc, ks, l4);
    if (t + 1 < NT) stageHalf(Bt, K, n0, kN1, Bdst, tid);
    __builtin_amdgcn_s_setprio(1);
#pragma unroll
    for (int mi = 0; mi < 4; ++mi)
#pragma unroll
      for (int j = 0; j < 2; ++j)
#pragma unroll
        for (int ks = 0; ks < 2; ++ks)
          acc[mi][j] = __builtin_amdgcn_mfma_f32_16x16x32_bf16(aLo[mi][ks], bFr[j][ks], acc[mi][j], 0, 0, 0);
    __builtin_amdgcn_s_setprio(0);
    // ---- phase 2: read A-hi; stage B1(t+1); MFMA Q(hi,lo)
#pragma unroll
    for (int mi = 0; mi < 4; ++mi)
#pragma unroll
      for (int ks = 0; ks < 2; ++ks)
        aHi[mi][ks] = readFrag128(Ah, 64 + mi * 16 + lc, ks, l4);
    if (t + 1 < NT) stageHalf(Bt, K, n0 + 128, kN1, Bdst + 8192, tid);
    __builtin_amdgcn_s_setprio(1);
#pragma unroll
    for (int mi = 0; mi < 4; ++mi)
#pragma unroll
      for (int j = 0; j < 2; ++j)
#pragma unroll
        for (int ks = 0; ks < 2; ++ks)
          acc[4 + mi][j] = __builtin_amdgcn_mfma_f32_16x16x32_bf16(aHi[mi][ks], bFr[j][ks], acc[4 + mi][j], 0, 0, 0);
    __builtin_amdgcn_s_setprio(0);
    // ---- phase 3: read B-hi; stage A(t+2) into ring slot
#pragma unroll
    for (int j = 0; j < 2; ++j)
#pragma unroll
      for (int ks = 0; ks < 2; ++ks)
        bFr[j][ks] = readFrag128(Bh, rBq + (2 + j) * 16 + lc, ks, l4);
    if (t + 2 < NT) {
      stageHalf(A, K, m0, kN2, Adst, tid);
      stageHalf(A, K, m0 + 128, kN2, Adst + 8192, tid);
    }
    __builtin_amdgcn_s_setprio(1);
#pragma unroll
    for (int mi = 0; mi < 4; ++mi)
#pragma unroll
      for (int j = 0; j < 2; ++j)
#pragma unroll
        for (int ks = 0; ks < 2; ++ks)
          acc[mi][2 + j] = __builtin_amdgcn_mfma_f32_16x16x32_bf16(aLo[mi][ks], bFr[j][ks], acc[mi][2 + j], 0, 0, 0);
    __builtin_amdgcn_s_setprio(0);
    // ---- phase 4: MFMA Q(hi,hi); counted vmcnt; single end-of-tile barrier
    __builtin_amdgcn_s_setprio(1);
#pragma unroll
    for (int mi = 0; mi < 4; ++mi)
#pragma unroll
      for (int j = 0; j < 2; ++j)
#pragma unroll
        for (int ks = 0; ks < 2; ++ks)
          acc[4 + mi][2 + j] = __builtin_amdgcn_mfma_f32_16x16x32_bf16(aHi[mi][ks], bFr[j][ks], acc[4 + mi][2 + j], 0, 0, 0);
    __builtin_amdgcn_s_setprio(0);
    if (t + 2 < NT) asm volatile("s_waitcnt vmcnt(4)" ::: "memory");
    else            asm volatile("s_waitcnt vmcnt(0)" ::: "memory");
    BAR();
    ab = (ab == 2) ? 0 : ab + 1;
  }
  // epilogue
  if constexpr (EPI == 3) {
    u16* swig = reinterpret_cast<u16*>(Cv);
    int scolB = (n0 >> 1) + wn * 32 + lc;
#pragma unroll
    for (int mi = 0; mi < 8; ++mi) {
      int row0 = m0 + wm * 128 + (mi >> 2) * 64 + (mi & 3) * 16 + l4 * 4;
#pragma unroll
      for (int jp = 0; jp < 2; ++jp)
#pragma unroll
        for (int jr = 0; jr < 4; ++jr) {
          float a = acc[mi][jp * 2][jr];
          float b3 = acc[mi][jp * 2 + 1][jr];
          float sv = a / (1.f + __expf(-a)) * b3;
          swig[(size_t)(row0 + jr) * 4096 + scolB + jp * 16] = f2bf(sv);
        }
    }
  } else {
    u16* Cb = reinterpret_cast<u16*>(Cv);
    int colB = n0 + wn * 64 + lc;
#pragma unroll
    for (int mi = 0; mi < 8; ++mi) {
      int row0 = m0 + wm * 128 + (mi >> 2) * 64 + (mi & 3) * 16 + l4 * 4;
#pragma unroll
      for (int j = 0; j < 4; ++j)
#pragma unroll
        for (int jr = 0; jr < 4; ++jr)
          Cb[(size_t)(row0 + jr) * N + colB + j * 16] = f2bf(acc[mi][j][jr]);
    }
  }
}

extern "C" void kernel_launch(void* const* d_in, const int* in_sizes, int n_in,
                              void* d_out, int out_size, void* d_ws, size_t ws_size,
                              hipStream_t stream) {
  const float* x    = (const float*)d_in[0];
  const float* rc   = (const float*)d_in[1];
  const float* rs   = (const float*)d_in[2];
  const float* cond = (const float*)d_in[3];
  const float* wq   = (const float*)d_in[4];
  const float* wk   = (const float*)d_in[5];
  const float* wv   = (const float*)d_in[6];
  const float* wo   = (const float*)d_in[7];
  const float* aaw  = (const float*)d_in[8];
  const float* aab  = (const float*)d_in[9];
  const float* afw  = (const float*)d_in[10];
  const float* afb  = (const float*)d_in[11];
  const float* w1   = (const float*)d_in[12];
  const float* w3   = (const float*)d_in[13];
  const float* w2   = (const float*)d_in[14];
  float* out = (float*)d_out;
  char* ws = (char*)d_ws;

  u16*   wt_qkv = (u16*)  (ws + 0);
  u16*   wt_o   = (u16*)  (ws + 6291456);
  u16*   wt_13  = (u16*)  (ws + 8388608);
  u16*   wt_2   = (u16*)  (ws + 25165824);
  float* modf   = (float*)(ws + 33554432);
  u16*   norm_b = (u16*)  (ws + 33603584);
  u16*   attn_b = (u16*)  (ws + 41992192);
  u16*   qkv_bf = (u16*)  (ws + 50380800);
  float* adpart = (float*)(ws + 50380800);
  u16*   hbuf_bf= (u16*)  (ws + 117489664);   // M x 1024 bf16
  u16*   swig_b = (u16*)  (ws + 134266880);

  {
    auto f2 = gemm8p<2>; auto f3 = gemm8p<3>;
    hipFuncSetAttribute((const void*)f2, hipFuncAttributeMaxDynamicSharedMemorySize, 163840);
    hipFuncSetAttribute((const void*)f3, hipFuncAttributeMaxDynamicSharedMemorySize, 163840);
  }

  prep_all<<<16768, 256, 0, stream>>>(wq, wk, wv, wo, w1, w3, w2, cond, aaw, afw,
                                      wt_qkv, wt_o, wt_13, wt_2, adpart);
  adaln_reduce<<<dim3(12, 4), 256, 0, stream>>>(adpart, aab, afb, modf);

  ln_mod_kernel<0><<<4096, 256, 0, stream>>>(x, modf, norm_b);
  gemm8p<2><<<dim3(192), 512, 163840, stream>>>(norm_b, wt_qkv, M_, 3072, 1024, qkv_bf);
  rope_k<<<8192, 256, 0, stream>>>(qkv_bf, rc, rs);
  attn_mfma<<<dim3(32, 16, 2), 256, 0, stream>>>(qkv_bf, rc, rs, attn_b);
  gemm64<0, 1><<<dim3(8, 64), 256, 0, stream>>>(attn_b, wt_o, M_, 1024, 1024, hbuf_bf, modf + 2048, x);
  ln_mod_kernel<1><<<4096, 256, 0, stream>>>(hbuf_bf, modf + 6144, norm_b);
  gemm8p<3><<<dim3(512), 512, 163840, stream>>>(norm_b, wt_13, M_, 8192, 1024, swig_b);
  gemm64<1, 0><<<dim3(8, 64), 256, 0, stream>>>(swig_b, wt_2, M_, 1024, 4096, out, modf + 6144 + 2048, hbuf_bf);
}